// Round 1
// baseline (2605.628 us; speedup 1.0000x reference)
//
#include <hip/hip_runtime.h>
#include <hip/hip_bf16.h>

#define H_    2048
#define NH_   16
#define KD_   1024
#define DK_   64
#define T_    1024
#define B_    2
#define M_    (B_*T_)     // 2048 rows
#define RL_   64

// ---------------------------------------------------------------------------
// xx = x + (shift(x) - x) * mu_x[h]
__global__ __launch_bounds__(256) void mix_mu_kernel(const float* __restrict__ x,
                                                     const float* __restrict__ mu,
                                                     float* __restrict__ xm) {
    int idx = blockIdx.x * 256 + threadIdx.x;      // grid covers M_*H_ exactly
    int h = idx & (H_ - 1);
    int t = (idx >> 11) & (T_ - 1);                // H_=2^11
    float xv = x[idx];
    float sh = (t > 0) ? x[idx - H_] : 0.f;
    xm[idx] = xv + (sh - xv) * mu[h];
}

// ---------------------------------------------------------------------------
// xm = x + (shift(x)-x) * (tanh_lr[bt, i] . Wx2[h, i, :] + x_bias[i,h])
__global__ __launch_bounds__(256) void musmix_kernel(const float* __restrict__ x,
                                                     const float* __restrict__ lr,
                                                     const float* __restrict__ Wx2,
                                                     const float* __restrict__ xbias,
                                                     float* __restrict__ xm, int branch) {
    int idx = blockIdx.x * 256 + threadIdx.x;
    int h = idx & (H_ - 1);
    int bt = idx >> 11;
    int t = bt & (T_ - 1);
    const float4* lr4 = (const float4*)(lr + (size_t)bt * 320 + branch * 64);
    const float4* w4  = (const float4*)(Wx2 + (size_t)h * 320 + branch * 64);
    float acc = xbias[branch * H_ + h];
    #pragma unroll
    for (int q = 0; q < 16; ++q) {
        float4 a = lr4[q];
        float4 b = w4[q];
        acc += a.x * b.x + a.y * b.y + a.z * b.z + a.w * b.w;
    }
    float xv = x[idx];
    float sh = (t > 0) ? x[idx - H_] : 0.f;
    xm[idx] = xv + (sh - xv) * acc;
}

// ---------------------------------------------------------------------------
// C[M][N] = epilogue(A[M][K] @ W[K][N]).  Tiles: BM=BN=64, BK=16, 256 thr, 4x4/thr.
// All M,N multiples of 64; K multiple of 16 (holds for every call here).
// EPI: 0 = none, 1 = tanh, 2 = +bias, 3 = exp(-exp(v + bias))
template<int EPI>
__global__ __launch_bounds__(256) void gemm_f32(const float* __restrict__ A,
                                                const float* __restrict__ W,
                                                const float* __restrict__ bias,
                                                float* __restrict__ C,
                                                int K, int lda, int ldb, int ldc) {
    __shared__ float As[16][68];   // [k][m], padded stride 68 (16B-aligned, conflict-lite)
    __shared__ float Bs[16][68];   // [k][n]
    int tid = threadIdx.x;
    int tx = tid & 15, ty = tid >> 4;
    int row0 = blockIdx.y * 64, col0 = blockIdx.x * 64;
    int am = tid >> 2, ak = (tid & 3) << 2;   // A loader: row am, k-offset ak (float4)
    int bk = tid >> 4, bn = (tid & 15) << 2;  // B loader: k row bk, col bn (float4)
    float acc[4][4] = {};
    for (int k0 = 0; k0 < K; k0 += 16) {
        float4 av = *(const float4*)&A[(size_t)(row0 + am) * lda + k0 + ak];
        float4 bv = *(const float4*)&W[(size_t)(k0 + bk) * ldb + col0 + bn];
        As[ak + 0][am] = av.x; As[ak + 1][am] = av.y;
        As[ak + 2][am] = av.z; As[ak + 3][am] = av.w;
        *(float4*)&Bs[bk][bn] = bv;
        __syncthreads();
        #pragma unroll
        for (int kk = 0; kk < 16; ++kk) {
            float4 a = *(const float4*)&As[kk][ty << 2];
            float4 b = *(const float4*)&Bs[kk][tx << 2];
            float aa[4] = {a.x, a.y, a.z, a.w};
            float bb[4] = {b.x, b.y, b.z, b.w};
            #pragma unroll
            for (int i = 0; i < 4; ++i)
                #pragma unroll
                for (int j = 0; j < 4; ++j)
                    acc[i][j] = fmaf(aa[i], bb[j], acc[i][j]);
        }
        __syncthreads();
    }
    #pragma unroll
    for (int i = 0; i < 4; ++i) {
        int r = row0 + (ty << 2) + i;
        #pragma unroll
        for (int j = 0; j < 4; ++j) {
            int c = col0 + (tx << 2) + j;
            float v = acc[i][j];
            if (EPI == 2 || EPI == 3) v += bias[c];
            if (EPI == 1) v = tanhf(v);
            if (EPI == 3) v = expf(-expf(v));
            C[(size_t)r * ldc + c] = v;
        }
    }
}

// ---------------------------------------------------------------------------
// Sequential linear-attention scan. One wave (64 lanes) per (b,h); lane = dv column.
// S[dk][lane] held in 64 registers. o_t = r.S + (sum r*u*k)*v[lane]; S = d*S + k*v[lane].
__global__ __launch_bounds__(64) void scan_kernel(const float* __restrict__ r,
                                                  const float* __restrict__ k,
                                                  const float* __restrict__ v,
                                                  const float* __restrict__ d,
                                                  const float* __restrict__ u,
                                                  float* __restrict__ o) {
    int b = blockIdx.x >> 4, h = blockIdx.x & 15;
    int lane = threadIdx.x;
    __shared__ float lr_[64], lk_[64], ld_[64];
    float u_lane = u[h * 64 + lane];
    float S[64];
    #pragma unroll
    for (int i = 0; i < 64; ++i) S[i] = 0.f;
    size_t idx = (size_t)(b * T_) * KD_ + h * 64 + lane;
    for (int t = 0; t < T_; ++t, idx += KD_) {
        float rv = r[idx], kv = k[idx], dv = d[idx], vv = v[idx];
        __syncthreads();
        lr_[lane] = rv; lk_[lane] = kv; ld_[lane] = dv;
        __syncthreads();
        float p = rv * u_lane * kv;          // bonus rank-1 term, reduced over dk
        #pragma unroll
        for (int m = 32; m >= 1; m >>= 1) p += __shfl_xor(p, m, 64);
        float oc = p * vv;
        #pragma unroll
        for (int q = 0; q < 16; ++q) {
            float4 R  = *(const float4*)&lr_[q * 4];
            float4 Kk = *(const float4*)&lk_[q * 4];
            float4 D  = *(const float4*)&ld_[q * 4];
            oc += R.x * S[q*4+0]; S[q*4+0] = D.x * S[q*4+0] + Kk.x * vv;
            oc += R.y * S[q*4+1]; S[q*4+1] = D.y * S[q*4+1] + Kk.y * vv;
            oc += R.z * S[q*4+2]; S[q*4+2] = D.z * S[q*4+2] + Kk.z * vv;
            oc += R.w * S[q*4+3]; S[q*4+3] = D.w * S[q*4+3] + Kk.w * vv;
        }
        o[idx] = oc;
    }
}

// ---------------------------------------------------------------------------
// Per-head layernorm + swish gate. One wave per (b,t,h) row of 64.
__global__ __launch_bounds__(256) void lngate_kernel(const float* __restrict__ o,
                                                     const float* __restrict__ g,
                                                     const float* __restrict__ lw,
                                                     const float* __restrict__ lb,
                                                     float* __restrict__ out) {
    int row = blockIdx.x * 4 + (threadIdx.x >> 6);
    int c = threadIdx.x & 63;
    size_t idx = (size_t)row * 64 + c;
    float oc = o[idx];
    float s = oc;
    #pragma unroll
    for (int m = 32; m >= 1; m >>= 1) s += __shfl_xor(s, m, 64);
    float mean = s * (1.f / 64.f);
    float dx = oc - mean;
    float s2 = dx * dx;
    #pragma unroll
    for (int m = 32; m >= 1; m >>= 1) s2 += __shfl_xor(s2, m, 64);
    float var = s2 * (1.f / 64.f);
    float on = dx * rsqrtf(var + 1e-5f) * lw[c] + lb[c];
    float gv = g[idx];
    out[idx] = on * gv / (1.f + expf(-gv));
}

// ---------------------------------------------------------------------------
extern "C" void kernel_launch(void* const* d_in, const int* in_sizes, int n_in,
                              void* d_out, int out_size, void* d_ws, size_t ws_size,
                              hipStream_t stream) {
    const float* x     = (const float*)d_in[0];
    const float* mu_x  = (const float*)d_in[1];
    const float* Wx1   = (const float*)d_in[2];
    const float* Wx2   = (const float*)d_in[3];
    const float* xbias = (const float*)d_in[4];
    const float* Wr    = (const float*)d_in[5];
    const float* Wk    = (const float*)d_in[6];
    const float* Wv    = (const float*)d_in[7];
    const float* Ww_a  = (const float*)d_in[8];
    const float* Ww_b  = (const float*)d_in[9];
    const float* bw    = (const float*)d_in[10];
    const float* Wg_a  = (const float*)d_in[11];
    const float* Wg_b  = (const float*)d_in[12];
    const float* bg    = (const float*)d_in[13];
    const float* bonus = (const float*)d_in[14];
    const float* ln_w  = (const float*)d_in[15];
    const float* ln_b  = (const float*)d_in[16];
    const float* Wo    = (const float*)d_in[17];
    float* out = (float*)d_out;

    // workspace layout (floats). total ~17.6M floats (~70 MB)
    float* ws  = (float*)d_ws;
    float* xm  = ws;                                // M_*H_     = 4,194,304
    float* lr  = xm  + (size_t)M_ * H_;             // M_*320
    float* hid = lr  + (size_t)M_ * 320;            // M_*64
    float* rb  = hid + (size_t)M_ * 64;             // M_*KD_
    float* kb  = rb  + (size_t)M_ * KD_;
    float* vb  = kb  + (size_t)M_ * KD_;
    float* db  = vb  + (size_t)M_ * KD_;            // decay
    float* gb  = db  + (size_t)M_ * KD_;            // raw gate
    float* ob  = gb  + (size_t)M_ * KD_;            // scan output
    float* gated = xm;                              // reuse xm after branches done

    const int elems = M_ * H_;
    dim3 blk(256);

    // 1. lr = tanh((x + delta*mu_x) @ Wx1)
    mix_mu_kernel<<<elems / 256, blk, 0, stream>>>(x, mu_x, xm);
    gemm_f32<1><<<dim3(320 / 64, M_ / 64), blk, 0, stream>>>(xm, Wx1, nullptr, lr,
                                                             H_, H_, 320, 320);

    // 2. branch r (i=0)
    musmix_kernel<<<elems / 256, blk, 0, stream>>>(x, lr, Wx2, xbias, xm, 0);
    gemm_f32<0><<<dim3(KD_ / 64, M_ / 64), blk, 0, stream>>>(xm, Wr, nullptr, rb,
                                                             H_, H_, KD_, KD_);
    // 3. branch w (i=1): decay = exp(-exp(tanh(xm@Ww_a)@Ww_b + bw))
    musmix_kernel<<<elems / 256, blk, 0, stream>>>(x, lr, Wx2, xbias, xm, 1);
    gemm_f32<1><<<dim3(1, M_ / 64), blk, 0, stream>>>(xm, Ww_a, nullptr, hid,
                                                      H_, H_, 64, 64);
    gemm_f32<3><<<dim3(KD_ / 64, M_ / 64), blk, 0, stream>>>(hid, Ww_b, bw, db,
                                                             64, 64, KD_, KD_);
    // 4. branch k (i=2)
    musmix_kernel<<<elems / 256, blk, 0, stream>>>(x, lr, Wx2, xbias, xm, 2);
    gemm_f32<0><<<dim3(KD_ / 64, M_ / 64), blk, 0, stream>>>(xm, Wk, nullptr, kb,
                                                             H_, H_, KD_, KD_);
    // 5. branch v (i=3)
    musmix_kernel<<<elems / 256, blk, 0, stream>>>(x, lr, Wx2, xbias, xm, 3);
    gemm_f32<0><<<dim3(KD_ / 64, M_ / 64), blk, 0, stream>>>(xm, Wv, nullptr, vb,
                                                             H_, H_, KD_, KD_);
    // 6. branch g (i=4): g = tanh(xm@Wg_a)@Wg_b + bg
    musmix_kernel<<<elems / 256, blk, 0, stream>>>(x, lr, Wx2, xbias, xm, 4);
    gemm_f32<1><<<dim3(1, M_ / 64), blk, 0, stream>>>(xm, Wg_a, nullptr, hid,
                                                      H_, H_, 64, 64);
    gemm_f32<2><<<dim3(KD_ / 64, M_ / 64), blk, 0, stream>>>(hid, Wg_b, bg, gb,
                                                             64, 64, KD_, KD_);

    // 7. sequential scan: 32 (b,h) chains, 1 wave each
    scan_kernel<<<B_ * NH_, 64, 0, stream>>>(rb, kb, vb, db, bonus, ob);

    // 8. per-head LN + swish gate (writes into xm region, reused as `gated`)
    lngate_kernel<<<(M_ * NH_) / 4, blk, 0, stream>>>(ob, gb, ln_w, ln_b, gated);

    // 9. out = gated @ Wo
    gemm_f32<0><<<dim3(H_ / 64, M_ / 64), blk, 0, stream>>>(gated, Wo, nullptr, out,
                                                            KD_, KD_, H_, H_);
}

// Round 2
// 1565.662 us; speedup vs baseline: 1.6642x; 1.6642x over previous
//
#include <hip/hip_runtime.h>
#include <hip/hip_bf16.h>

#define H_    2048
#define NH_   16
#define KD_   1024
#define DK_   64
#define T_    1024
#define B_    2
#define M_    (B_*T_)     // 2048 rows
#define RL_   64
#define CC_   32          // scan chunk length
#define NC_   (T_/CC_)    // 32 chunks per sequence

// ---------------------------------------------------------------------------
// xx = x + (shift(x) - x) * mu_x[h]
__global__ __launch_bounds__(256) void mix_mu_kernel(const float* __restrict__ x,
                                                     const float* __restrict__ mu,
                                                     float* __restrict__ xm) {
    int idx = blockIdx.x * 256 + threadIdx.x;
    int h = idx & (H_ - 1);
    int t = (idx >> 11) & (T_ - 1);
    float xv = x[idx];
    float sh = (t > 0) ? x[idx - H_] : 0.f;
    xm[idx] = xv + (sh - xv) * mu[h];
}

// ---------------------------------------------------------------------------
// xm = x + (shift(x)-x) * (tanh_lr[bt, i] . Wx2[h, i, :] + x_bias[i,h])
__global__ __launch_bounds__(256) void musmix_kernel(const float* __restrict__ x,
                                                     const float* __restrict__ lr,
                                                     const float* __restrict__ Wx2,
                                                     const float* __restrict__ xbias,
                                                     float* __restrict__ xm, int branch) {
    int idx = blockIdx.x * 256 + threadIdx.x;
    int h = idx & (H_ - 1);
    int bt = idx >> 11;
    int t = bt & (T_ - 1);
    const float4* lr4 = (const float4*)(lr + (size_t)bt * 320 + branch * 64);
    const float4* w4  = (const float4*)(Wx2 + (size_t)h * 320 + branch * 64);
    float acc = xbias[branch * H_ + h];
    #pragma unroll
    for (int q = 0; q < 16; ++q) {
        float4 a = lr4[q];
        float4 b = w4[q];
        acc += a.x * b.x + a.y * b.y + a.z * b.z + a.w * b.w;
    }
    float xv = x[idx];
    float sh = (t > 0) ? x[idx - H_] : 0.f;
    xm[idx] = xv + (sh - xv) * acc;
}

// ---------------------------------------------------------------------------
// C[M][N] = epilogue(A[M][K] @ W[K][N]).  Tiles: BM=BN=64, BK=16, 256 thr, 4x4/thr.
// Register-prefetch software pipeline: next K-tile global load overlaps compute.
// EPI: 0 = none, 1 = tanh, 2 = +bias, 3 = log-decay: -exp(v + bias)
template<int EPI>
__global__ __launch_bounds__(256) void gemm_f32(const float* __restrict__ A,
                                                const float* __restrict__ W,
                                                const float* __restrict__ bias,
                                                float* __restrict__ C,
                                                int K, int lda, int ldb, int ldc) {
    __shared__ float As[16][68];
    __shared__ float Bs[16][68];
    int tid = threadIdx.x;
    int tx = tid & 15, ty = tid >> 4;
    int row0 = blockIdx.y * 64, col0 = blockIdx.x * 64;
    int am = tid >> 2, ak = (tid & 3) << 2;
    int bk = tid >> 4, bn = (tid & 15) << 2;
    float acc[4][4] = {};
    float4 av = *(const float4*)&A[(size_t)(row0 + am) * lda + ak];
    float4 bv = *(const float4*)&W[(size_t)bk * ldb + col0 + bn];
    for (int k0 = 0; k0 < K; k0 += 16) {
        __syncthreads();   // prior compute done before overwriting LDS
        As[ak + 0][am] = av.x; As[ak + 1][am] = av.y;
        As[ak + 2][am] = av.z; As[ak + 3][am] = av.w;
        *(float4*)&Bs[bk][bn] = bv;
        __syncthreads();
        if (k0 + 16 < K) {
            av = *(const float4*)&A[(size_t)(row0 + am) * lda + k0 + 16 + ak];
            bv = *(const float4*)&W[(size_t)(k0 + 16 + bk) * ldb + col0 + bn];
        }
        #pragma unroll
        for (int kk = 0; kk < 16; ++kk) {
            float4 a = *(const float4*)&As[kk][ty << 2];
            float4 b = *(const float4*)&Bs[kk][tx << 2];
            float aa[4] = {a.x, a.y, a.z, a.w};
            float bb[4] = {b.x, b.y, b.z, b.w};
            #pragma unroll
            for (int i = 0; i < 4; ++i)
                #pragma unroll
                for (int j = 0; j < 4; ++j)
                    acc[i][j] = fmaf(aa[i], bb[j], acc[i][j]);
        }
    }
    #pragma unroll
    for (int i = 0; i < 4; ++i) {
        int r = row0 + (ty << 2) + i;
        #pragma unroll
        for (int j = 0; j < 4; ++j) {
            int c = col0 + (tx << 2) + j;
            float v = acc[i][j];
            if (EPI == 2 || EPI == 3) v += bias[c];
            if (EPI == 1) v = tanhf(v);
            if (EPI == 3) v = -expf(v);   // store LOG decay
            C[(size_t)r * ldc + c] = v;
        }
    }
}

// ---------------------------------------------------------------------------
// Chunked scan, phase A: per (bh, chunk) block compute intra-chunk outputs,
// decayed r (rt, written in place over r), chunk summary B and total decay D.
// ld holds log-decay. bid = bh*NC_ + c.
__global__ __launch_bounds__(256) void scan_chunkA(const float* r, const float* k,
                                                   const float* v, const float* ld,
                                                   const float* u,
                                                   float* rt, float* ointra,
                                                   float* Bc, float* Dc) {
    __shared__ float sR[CC_][68], sK[CC_][68], sV[CC_][68], sW[CC_][68];
    __shared__ float wc[CC_ + 1][64];
    __shared__ float sA[CC_][36];
    __shared__ float diag[CC_];
    __shared__ float sU[64];
    int bid = blockIdx.x;
    int bh = bid >> 5, c = bid & (NC_ - 1);
    int b = bh >> 4, h = bh & 15;
    int tid = threadIdx.x;
    size_t base = ((size_t)(b * T_ + c * CC_)) * KD_ + h * 64;

    for (int q = tid; q < CC_ * 16; q += 256) {       // 512 float4 loads per array
        int row = q >> 4, col4 = (q & 15) << 2;
        size_t gi = base + (size_t)row * KD_ + col4;
        *(float4*)&sR[row][col4] = *(const float4*)&r[gi];
        *(float4*)&sK[row][col4] = *(const float4*)&k[gi];
        *(float4*)&sV[row][col4] = *(const float4*)&v[gi];
        *(float4*)&sW[row][col4] = *(const float4*)&ld[gi];
    }
    if (tid < 64) sU[tid] = u[h * 64 + tid];
    __syncthreads();

    // prefix-sum of log-decay per dk column i (exclusive: wc[0]=0)
    if (tid < 64) {
        float acc = 0.f;
        wc[0][tid] = 0.f;
        #pragma unroll
        for (int s = 0; s < CC_; ++s) { acc += sW[s][tid]; wc[s + 1][tid] = acc; }
    }
    // diag[tau] = sum_i r*u*k  (bonus term)
    {
        int tau = tid >> 3, g = tid & 7;
        float p = 0.f;
        #pragma unroll
        for (int q = 0; q < 8; ++q) {
            int i = g * 8 + q;
            p += sR[tau][i] * sU[i] * sK[tau][i];
        }
        p += __shfl_xor(p, 1, 64); p += __shfl_xor(p, 2, 64); p += __shfl_xor(p, 4, 64);
        if (g == 0) diag[tau] = p;
    }
    __syncthreads();

    // elementwise: rt = r*exp(wc_s); kt = k*exp(-wc_{s+1}); b = k*exp(wc_C - wc_{s+1})
    // overwrite: sR <- rt, sW <- kt, sK <- b.  Also write rt to global.
    for (int q = tid; q < CC_ * 64; q += 256) {
        int s = q >> 6, i = q & 63;
        float wcs  = wc[s][i];
        float wcs1 = wc[s + 1][i];
        float wcc  = wc[CC_][i];
        float rt_ = sR[s][i] * expf(wcs);
        float kt_ = sK[s][i] * expf(-wcs1);
        float bb  = sK[s][i] * expf(wcc - wcs1);
        sR[s][i] = rt_;
        sW[s][i] = kt_;
        sK[s][i] = bb;
        rt[base + (size_t)s * KD_ + i] = rt_;
    }
    if (tid < 64) Dc[(size_t)bid * 64 + tid] = expf(wc[CC_][tid]);
    __syncthreads();

    // score A[tau][sig] = rt[tau] . kt[sig]  (sig<tau), diag on sig==tau, else 0
    {
        int tau = tid >> 3, s0 = (tid & 7) * 4;
        float a0 = 0, a1 = 0, a2 = 0, a3 = 0;
        for (int i = 0; i < 64; i += 4) {
            float4 rr = *(const float4*)&sR[tau][i];
            float4 k0v = *(const float4*)&sW[s0 + 0][i];
            float4 k1v = *(const float4*)&sW[s0 + 1][i];
            float4 k2v = *(const float4*)&sW[s0 + 2][i];
            float4 k3v = *(const float4*)&sW[s0 + 3][i];
            a0 += rr.x * k0v.x + rr.y * k0v.y + rr.z * k0v.z + rr.w * k0v.w;
            a1 += rr.x * k1v.x + rr.y * k1v.y + rr.z * k1v.z + rr.w * k1v.w;
            a2 += rr.x * k2v.x + rr.y * k2v.y + rr.z * k2v.z + rr.w * k2v.w;
            a3 += rr.x * k3v.x + rr.y * k3v.y + rr.z * k3v.z + rr.w * k3v.w;
        }
        sA[tau][s0 + 0] = (s0 + 0 < tau) ? a0 : ((s0 + 0 == tau) ? diag[tau] : 0.f);
        sA[tau][s0 + 1] = (s0 + 1 < tau) ? a1 : ((s0 + 1 == tau) ? diag[tau] : 0.f);
        sA[tau][s0 + 2] = (s0 + 2 < tau) ? a2 : ((s0 + 2 == tau) ? diag[tau] : 0.f);
        sA[tau][s0 + 3] = (s0 + 3 < tau) ? a3 : ((s0 + 3 == tau) ? diag[tau] : 0.f);
    }
    __syncthreads();

    // o_intra[tau][j] = sum_sig A[tau][sig] * v[sig][j]
    {
        int tau = tid >> 3, j0 = (tid & 7) * 8;
        float o_[8] __attribute__((aligned(16))) = {};
        for (int s = 0; s < CC_; ++s) {
            float a = sA[tau][s];
            #pragma unroll
            for (int q = 0; q < 8; ++q) o_[q] += a * sV[s][j0 + q];
        }
        size_t ob = base + (size_t)tau * KD_ + j0;
        *(float4*)&ointra[ob]     = *(float4*)&o_[0];
        *(float4*)&ointra[ob + 4] = *(float4*)&o_[4];
    }
    // B[i][j] = sum_sig b[sig][i] * v[sig][j]
    {
        int i = tid >> 2, j0 = (tid & 3) * 16;
        float bacc[16] __attribute__((aligned(16))) = {};
        for (int s = 0; s < CC_; ++s) {
            float bi = sK[s][i];
            #pragma unroll
            for (int q = 0; q < 16; ++q) bacc[q] += bi * sV[s][j0 + q];
        }
        size_t bb = ((size_t)bid << 12) + i * 64 + j0;
        *(float4*)&Bc[bb + 0]  = *(float4*)&bacc[0];
        *(float4*)&Bc[bb + 4]  = *(float4*)&bacc[4];
        *(float4*)&Bc[bb + 8]  = *(float4*)&bacc[8];
        *(float4*)&Bc[bb + 12] = *(float4*)&bacc[12];
    }
}

// ---------------------------------------------------------------------------
// Phase B: elementwise inter-chunk recurrence S <- D*S + B per (bh,i,j).
// BS[c] is overwritten in place with S_in (state at chunk start).
__global__ __launch_bounds__(256) void scan_chunkB(float* BS, const float* __restrict__ Dc) {
    int g = blockIdx.x * 256 + threadIdx.x;   // 32*64*64 = 131072 threads
    int bh = g >> 12, ij = g & 4095, i = ij >> 6;
    float S = 0.f;
    size_t base = ((size_t)bh << 17) + ij;
    for (int c = 0; c < NC_; ++c) {
        size_t idx = base + ((size_t)c << 12);
        float bv = BS[idx];
        float d = Dc[(size_t)(bh * NC_ + c) * 64 + i];
        BS[idx] = S;
        S = d * S + bv;
    }
}

// ---------------------------------------------------------------------------
// Phase C: o[tau][j] += rt[tau] . S_in[:, j]
__global__ __launch_bounds__(256) void scan_chunkC(const float* __restrict__ rt,
                                                   const float* __restrict__ BS,
                                                   float* o) {
    __shared__ float sS[64][64];
    __shared__ float sRt[CC_][68];
    int bid = blockIdx.x;
    int bh = bid >> 5, c = bid & (NC_ - 1);
    int b = bh >> 4, h = bh & 15;
    int tid = threadIdx.x;
    size_t sbase = ((size_t)bid) << 12;
    for (int q = tid; q < 1024; q += 256)
        *(float4*)&sS[q >> 4][(q & 15) << 2] = *(const float4*)&BS[sbase + (q << 2)];
    size_t base = ((size_t)(b * T_ + c * CC_)) * KD_ + h * 64;
    for (int q = tid; q < CC_ * 16; q += 256) {
        int row = q >> 4, col4 = (q & 15) << 2;
        *(float4*)&sRt[row][col4] = *(const float4*)&rt[base + (size_t)row * KD_ + col4];
    }
    __syncthreads();
    int tau = tid >> 3, j0 = (tid & 7) * 8;
    size_t obase = base + (size_t)tau * KD_ + j0;
    float acc[8] __attribute__((aligned(16)));
    *(float4*)&acc[0] = *(const float4*)&o[obase];
    *(float4*)&acc[4] = *(const float4*)&o[obase + 4];
    for (int i = 0; i < 64; ++i) {
        float a = sRt[tau][i];
        #pragma unroll
        for (int q = 0; q < 8; ++q) acc[q] += a * sS[i][j0 + q];
    }
    *(float4*)&o[obase]     = *(float4*)&acc[0];
    *(float4*)&o[obase + 4] = *(float4*)&acc[4];
}

// ---------------------------------------------------------------------------
// Per-head layernorm + swish gate. One wave per (b,t,h) row of 64.
__global__ __launch_bounds__(256) void lngate_kernel(const float* __restrict__ o,
                                                     const float* __restrict__ g,
                                                     const float* __restrict__ lw,
                                                     const float* __restrict__ lb,
                                                     float* __restrict__ out) {
    int row = blockIdx.x * 4 + (threadIdx.x >> 6);
    int c = threadIdx.x & 63;
    size_t idx = (size_t)row * 64 + c;
    float oc = o[idx];
    float s = oc;
    #pragma unroll
    for (int m = 32; m >= 1; m >>= 1) s += __shfl_xor(s, m, 64);
    float mean = s * (1.f / 64.f);
    float dx = oc - mean;
    float s2 = dx * dx;
    #pragma unroll
    for (int m = 32; m >= 1; m >>= 1) s2 += __shfl_xor(s2, m, 64);
    float var = s2 * (1.f / 64.f);
    float on = dx * rsqrtf(var + 1e-5f) * lw[c] + lb[c];
    float gv = g[idx];
    out[idx] = on * gv / (1.f + expf(-gv));
}

// ---------------------------------------------------------------------------
extern "C" void kernel_launch(void* const* d_in, const int* in_sizes, int n_in,
                              void* d_out, int out_size, void* d_ws, size_t ws_size,
                              hipStream_t stream) {
    const float* x     = (const float*)d_in[0];
    const float* mu_x  = (const float*)d_in[1];
    const float* Wx1   = (const float*)d_in[2];
    const float* Wx2   = (const float*)d_in[3];
    const float* xbias = (const float*)d_in[4];
    const float* Wr    = (const float*)d_in[5];
    const float* Wk    = (const float*)d_in[6];
    const float* Wv    = (const float*)d_in[7];
    const float* Ww_a  = (const float*)d_in[8];
    const float* Ww_b  = (const float*)d_in[9];
    const float* bw    = (const float*)d_in[10];
    const float* Wg_a  = (const float*)d_in[11];
    const float* Wg_b  = (const float*)d_in[12];
    const float* bg    = (const float*)d_in[13];
    const float* bonus = (const float*)d_in[14];
    const float* ln_w  = (const float*)d_in[15];
    const float* ln_b  = (const float*)d_in[16];
    const float* Wo    = (const float*)d_in[17];
    float* out = (float*)d_out;

    // workspace layout (floats), ~84 MB total
    float* ws  = (float*)d_ws;
    float* xm  = ws;                                // M_*H_  (16 MB)
    float* lr  = xm  + (size_t)M_ * H_;             // M_*320
    float* hid = lr  + (size_t)M_ * 320;            // M_*64
    float* rb  = hid + (size_t)M_ * 64;             // M_*KD_  (rt in-place later)
    float* kb  = rb  + (size_t)M_ * KD_;
    float* vb  = kb  + (size_t)M_ * KD_;
    float* db  = vb  + (size_t)M_ * KD_;            // log-decay
    float* gb  = db  + (size_t)M_ * KD_;            // raw gate
    float* ob  = gb  + (size_t)M_ * KD_;            // o_intra then final o
    float* BS  = ob  + (size_t)M_ * KD_;            // 1024*64*64 (B then S_in, 16 MB)
    float* Dc  = BS  + (size_t)1024 * 4096;         // 1024*64
    float* gated = xm;                              // reuse xm after branches done

    const int elems = M_ * H_;
    dim3 blk(256);

    // 1. lr = tanh((x + delta*mu_x) @ Wx1)
    mix_mu_kernel<<<elems / 256, blk, 0, stream>>>(x, mu_x, xm);
    gemm_f32<1><<<dim3(320 / 64, M_ / 64), blk, 0, stream>>>(xm, Wx1, nullptr, lr,
                                                             H_, H_, 320, 320);
    // 2. branch r
    musmix_kernel<<<elems / 256, blk, 0, stream>>>(x, lr, Wx2, xbias, xm, 0);
    gemm_f32<0><<<dim3(KD_ / 64, M_ / 64), blk, 0, stream>>>(xm, Wr, nullptr, rb,
                                                             H_, H_, KD_, KD_);
    // 3. branch w: log-decay = -exp(tanh(xm@Ww_a)@Ww_b + bw)
    musmix_kernel<<<elems / 256, blk, 0, stream>>>(x, lr, Wx2, xbias, xm, 1);
    gemm_f32<1><<<dim3(1, M_ / 64), blk, 0, stream>>>(xm, Ww_a, nullptr, hid,
                                                      H_, H_, 64, 64);
    gemm_f32<3><<<dim3(KD_ / 64, M_ / 64), blk, 0, stream>>>(hid, Ww_b, bw, db,
                                                             64, 64, KD_, KD_);
    // 4. branch k
    musmix_kernel<<<elems / 256, blk, 0, stream>>>(x, lr, Wx2, xbias, xm, 2);
    gemm_f32<0><<<dim3(KD_ / 64, M_ / 64), blk, 0, stream>>>(xm, Wk, nullptr, kb,
                                                             H_, H_, KD_, KD_);
    // 5. branch v
    musmix_kernel<<<elems / 256, blk, 0, stream>>>(x, lr, Wx2, xbias, xm, 3);
    gemm_f32<0><<<dim3(KD_ / 64, M_ / 64), blk, 0, stream>>>(xm, Wv, nullptr, vb,
                                                             H_, H_, KD_, KD_);
    // 6. branch g
    musmix_kernel<<<elems / 256, blk, 0, stream>>>(x, lr, Wx2, xbias, xm, 4);
    gemm_f32<1><<<dim3(1, M_ / 64), blk, 0, stream>>>(xm, Wg_a, nullptr, hid,
                                                      H_, H_, 64, 64);
    gemm_f32<2><<<dim3(KD_ / 64, M_ / 64), blk, 0, stream>>>(hid, Wg_b, bg, gb,
                                                             64, 64, KD_, KD_);

    // 7. chunk-parallel scan
    scan_chunkA<<<B_ * NH_ * NC_, blk, 0, stream>>>(rb, kb, vb, db, bonus,
                                                    rb /*rt in place*/, ob, BS, Dc);
    scan_chunkB<<<(B_ * NH_ * 4096) / 256, blk, 0, stream>>>(BS, Dc);
    scan_chunkC<<<B_ * NH_ * NC_, blk, 0, stream>>>(rb, BS, ob);

    // 8. per-head LN + swish gate
    lngate_kernel<<<(M_ * NH_) / 4, blk, 0, stream>>>(ob, gb, ln_w, ln_b, gated);

    // 9. out = gated @ Wo
    gemm_f32<0><<<dim3(H_ / 64, M_ / 64), blk, 0, stream>>>(gated, Wo, nullptr, out,
                                                            KD_, KD_, H_, H_);
}

// Round 3
// 893.389 us; speedup vs baseline: 2.9166x; 1.7525x over previous
//
#include <hip/hip_runtime.h>
#include <hip/hip_bf16.h>

#define H_    2048
#define NH_   16
#define KD_   1024
#define DK_   64
#define T_    1024
#define B_    2
#define M_    (B_*T_)     // 2048 rows
#define RL_   64
#define CC_   32          // scan chunk length
#define NC_   (T_/CC_)    // 32 chunks per sequence

// ---------------------------------------------------------------------------
// xx = x + (shift(x) - x) * mu_x[h]
__global__ __launch_bounds__(256) void mix_mu_kernel(const float* __restrict__ x,
                                                     const float* __restrict__ mu,
                                                     float* __restrict__ xm) {
    int idx = blockIdx.x * 256 + threadIdx.x;
    int h = idx & (H_ - 1);
    int t = (idx >> 11) & (T_ - 1);
    float xv = x[idx];
    float sh = (t > 0) ? x[idx - H_] : 0.f;
    xm[idx] = xv + (sh - xv) * mu[h];
}

// ---------------------------------------------------------------------------
// Fused: mus[bt][h] = lr[bt, branch, :] . Wx2[h, branch, :] + bias[branch][h]
//        xm[bt][h] = x + (shift(x)-x) * mus      (K=64 GEMM + lerp epilogue)
// Tile 64x64, 256 threads, 4x4 per thread. lr/Wx2 staged via coalesced float4.
__global__ __launch_bounds__(256) void musgemm_kernel(const float* __restrict__ x,
                                                      const float* __restrict__ lr,
                                                      const float* __restrict__ Wx2,
                                                      const float* __restrict__ xbias,
                                                      float* __restrict__ xm, int branch) {
    __shared__ float sL[64][68];   // [bt][k]
    __shared__ float sW[64][68];   // [h][k]
    int tid = threadIdx.x;
    int tx = tid & 15, ty = tid >> 4;
    int col0 = blockIdx.x * 64;    // h
    int row0 = blockIdx.y * 64;    // bt
    for (int q = tid; q < 1024; q += 256) {
        int r = q >> 4, k4 = (q & 15) << 2;
        *(float4*)&sL[r][k4] = *(const float4*)&lr[(size_t)(row0 + r) * 320 + branch * 64 + k4];
        *(float4*)&sW[r][k4] = *(const float4*)&Wx2[(size_t)(col0 + r) * 320 + branch * 64 + k4];
    }
    __syncthreads();
    float acc[4][4] = {};
    for (int k = 0; k < 64; k += 4) {
        float4 a[4], b[4];
        #pragma unroll
        for (int i = 0; i < 4; ++i) a[i] = *(const float4*)&sL[(ty << 2) + i][k];
        #pragma unroll
        for (int j = 0; j < 4; ++j) b[j] = *(const float4*)&sW[(tx << 2) + j][k];
        #pragma unroll
        for (int i = 0; i < 4; ++i)
            #pragma unroll
            for (int j = 0; j < 4; ++j)
                acc[i][j] += a[i].x * b[j].x + a[i].y * b[j].y
                           + a[i].z * b[j].z + a[i].w * b[j].w;
    }
    float4 bias4 = *(const float4*)&xbias[branch * H_ + col0 + (tx << 2)];
    float bb[4] = {bias4.x, bias4.y, bias4.z, bias4.w};
    #pragma unroll
    for (int i = 0; i < 4; ++i) {
        int r = row0 + (ty << 2) + i;
        int t = r & (T_ - 1);
        const float* xrow = &x[(size_t)r * H_ + col0 + (tx << 2)];
        float4 xv = *(const float4*)xrow;
        float4 sh = make_float4(0.f, 0.f, 0.f, 0.f);
        if (t > 0) sh = *(const float4*)(xrow - H_);
        float4 o;
        o.x = xv.x + (sh.x - xv.x) * (acc[i][0] + bb[0]);
        o.y = xv.y + (sh.y - xv.y) * (acc[i][1] + bb[1]);
        o.z = xv.z + (sh.z - xv.z) * (acc[i][2] + bb[2]);
        o.w = xv.w + (sh.w - xv.w) * (acc[i][3] + bb[3]);
        *(float4*)&xm[(size_t)r * H_ + col0 + (tx << 2)] = o;
    }
}

// ---------------------------------------------------------------------------
// C[M][N] = epilogue(A[M][K] @ W[K][N]).  Tiles: BM=BN=64, BK=16, 256 thr, 4x4/thr.
// Register-prefetch software pipeline: next K-tile global load overlaps compute.
// EPI: 0 = none, 1 = tanh, 2 = +bias, 3 = log-decay: -exp(v + bias)
template<int EPI>
__global__ __launch_bounds__(256) void gemm_f32(const float* __restrict__ A,
                                                const float* __restrict__ W,
                                                const float* __restrict__ bias,
                                                float* __restrict__ C,
                                                int K, int lda, int ldb, int ldc) {
    __shared__ float As[16][68];
    __shared__ float Bs[16][68];
    int tid = threadIdx.x;
    int tx = tid & 15, ty = tid >> 4;
    int row0 = blockIdx.y * 64, col0 = blockIdx.x * 64;
    int am = tid >> 2, ak = (tid & 3) << 2;
    int bk = tid >> 4, bn = (tid & 15) << 2;
    float acc[4][4] = {};
    float4 av = *(const float4*)&A[(size_t)(row0 + am) * lda + ak];
    float4 bv = *(const float4*)&W[(size_t)bk * ldb + col0 + bn];
    for (int k0 = 0; k0 < K; k0 += 16) {
        __syncthreads();
        As[ak + 0][am] = av.x; As[ak + 1][am] = av.y;
        As[ak + 2][am] = av.z; As[ak + 3][am] = av.w;
        *(float4*)&Bs[bk][bn] = bv;
        __syncthreads();
        if (k0 + 16 < K) {
            av = *(const float4*)&A[(size_t)(row0 + am) * lda + k0 + 16 + ak];
            bv = *(const float4*)&W[(size_t)(k0 + 16 + bk) * ldb + col0 + bn];
        }
        #pragma unroll
        for (int kk = 0; kk < 16; ++kk) {
            float4 a = *(const float4*)&As[kk][ty << 2];
            float4 b = *(const float4*)&Bs[kk][tx << 2];
            float aa[4] = {a.x, a.y, a.z, a.w};
            float bb[4] = {b.x, b.y, b.z, b.w};
            #pragma unroll
            for (int i = 0; i < 4; ++i)
                #pragma unroll
                for (int j = 0; j < 4; ++j)
                    acc[i][j] = fmaf(aa[i], bb[j], acc[i][j]);
        }
    }
    #pragma unroll
    for (int i = 0; i < 4; ++i) {
        int r = row0 + (ty << 2) + i;
        #pragma unroll
        for (int j = 0; j < 4; ++j) {
            int c = col0 + (tx << 2) + j;
            float v = acc[i][j];
            if (EPI == 2 || EPI == 3) v += bias[c];
            if (EPI == 1) v = tanhf(v);
            if (EPI == 3) v = -expf(v);   // store LOG decay
            C[(size_t)r * ldc + c] = v;
        }
    }
}

// ---------------------------------------------------------------------------
// Chunked scan, phase A.
__global__ __launch_bounds__(256) void scan_chunkA(const float* r, const float* k,
                                                   const float* v, const float* ld,
                                                   const float* u,
                                                   float* rt, float* ointra,
                                                   float* Bc, float* Dc) {
    __shared__ float sR[CC_][68], sK[CC_][68], sV[CC_][68], sW[CC_][68];
    __shared__ float wc[CC_ + 1][64];
    __shared__ float sA[CC_][36];
    __shared__ float diag[CC_];
    __shared__ float sU[64];
    int bid = blockIdx.x;
    int bh = bid >> 5, c = bid & (NC_ - 1);
    int b = bh >> 4, h = bh & 15;
    int tid = threadIdx.x;
    size_t base = ((size_t)(b * T_ + c * CC_)) * KD_ + h * 64;

    for (int q = tid; q < CC_ * 16; q += 256) {
        int row = q >> 4, col4 = (q & 15) << 2;
        size_t gi = base + (size_t)row * KD_ + col4;
        *(float4*)&sR[row][col4] = *(const float4*)&r[gi];
        *(float4*)&sK[row][col4] = *(const float4*)&k[gi];
        *(float4*)&sV[row][col4] = *(const float4*)&v[gi];
        *(float4*)&sW[row][col4] = *(const float4*)&ld[gi];
    }
    if (tid < 64) sU[tid] = u[h * 64 + tid];
    __syncthreads();

    if (tid < 64) {
        float acc = 0.f;
        wc[0][tid] = 0.f;
        #pragma unroll
        for (int s = 0; s < CC_; ++s) { acc += sW[s][tid]; wc[s + 1][tid] = acc; }
    }
    {
        int tau = tid >> 3, g = tid & 7;
        float p = 0.f;
        #pragma unroll
        for (int q = 0; q < 8; ++q) {
            int i = g * 8 + q;
            p += sR[tau][i] * sU[i] * sK[tau][i];
        }
        p += __shfl_xor(p, 1, 64); p += __shfl_xor(p, 2, 64); p += __shfl_xor(p, 4, 64);
        if (g == 0) diag[tau] = p;
    }
    __syncthreads();

    for (int q = tid; q < CC_ * 64; q += 256) {
        int s = q >> 6, i = q & 63;
        float wcs  = wc[s][i];
        float wcs1 = wc[s + 1][i];
        float wcc  = wc[CC_][i];
        float rt_ = sR[s][i] * expf(wcs);
        float kt_ = sK[s][i] * expf(-wcs1);
        float bb  = sK[s][i] * expf(wcc - wcs1);
        sR[s][i] = rt_;
        sW[s][i] = kt_;
        sK[s][i] = bb;
        rt[base + (size_t)s * KD_ + i] = rt_;
    }
    if (tid < 64) Dc[(size_t)bid * 64 + tid] = expf(wc[CC_][tid]);
    __syncthreads();

    {
        int tau = tid >> 3, s0 = (tid & 7) * 4;
        float a0 = 0, a1 = 0, a2 = 0, a3 = 0;
        for (int i = 0; i < 64; i += 4) {
            float4 rr = *(const float4*)&sR[tau][i];
            float4 k0v = *(const float4*)&sW[s0 + 0][i];
            float4 k1v = *(const float4*)&sW[s0 + 1][i];
            float4 k2v = *(const float4*)&sW[s0 + 2][i];
            float4 k3v = *(const float4*)&sW[s0 + 3][i];
            a0 += rr.x * k0v.x + rr.y * k0v.y + rr.z * k0v.z + rr.w * k0v.w;
            a1 += rr.x * k1v.x + rr.y * k1v.y + rr.z * k1v.z + rr.w * k1v.w;
            a2 += rr.x * k2v.x + rr.y * k2v.y + rr.z * k2v.z + rr.w * k2v.w;
            a3 += rr.x * k3v.x + rr.y * k3v.y + rr.z * k3v.z + rr.w * k3v.w;
        }
        sA[tau][s0 + 0] = (s0 + 0 < tau) ? a0 : ((s0 + 0 == tau) ? diag[tau] : 0.f);
        sA[tau][s0 + 1] = (s0 + 1 < tau) ? a1 : ((s0 + 1 == tau) ? diag[tau] : 0.f);
        sA[tau][s0 + 2] = (s0 + 2 < tau) ? a2 : ((s0 + 2 == tau) ? diag[tau] : 0.f);
        sA[tau][s0 + 3] = (s0 + 3 < tau) ? a3 : ((s0 + 3 == tau) ? diag[tau] : 0.f);
    }
    __syncthreads();

    {
        int tau = tid >> 3, j0 = (tid & 7) * 8;
        float o_[8] __attribute__((aligned(16))) = {};
        for (int s = 0; s < CC_; ++s) {
            float a = sA[tau][s];
            #pragma unroll
            for (int q = 0; q < 8; ++q) o_[q] += a * sV[s][j0 + q];
        }
        size_t ob = base + (size_t)tau * KD_ + j0;
        *(float4*)&ointra[ob]     = *(float4*)&o_[0];
        *(float4*)&ointra[ob + 4] = *(float4*)&o_[4];
    }
    {
        int i = tid >> 2, j0 = (tid & 3) * 16;
        float bacc[16] __attribute__((aligned(16))) = {};
        for (int s = 0; s < CC_; ++s) {
            float bi = sK[s][i];
            #pragma unroll
            for (int q = 0; q < 16; ++q) bacc[q] += bi * sV[s][j0 + q];
        }
        size_t bb = ((size_t)bid << 12) + i * 64 + j0;
        *(float4*)&Bc[bb + 0]  = *(float4*)&bacc[0];
        *(float4*)&Bc[bb + 4]  = *(float4*)&bacc[4];
        *(float4*)&Bc[bb + 8]  = *(float4*)&bacc[8];
        *(float4*)&Bc[bb + 12] = *(float4*)&bacc[12];
    }
}

// ---------------------------------------------------------------------------
// Phase B: elementwise inter-chunk recurrence S <- D*S + B per (bh,i,j).
__global__ __launch_bounds__(256) void scan_chunkB(float* BS, const float* __restrict__ Dc) {
    int g = blockIdx.x * 256 + threadIdx.x;
    int bh = g >> 12, ij = g & 4095, i = ij >> 6;
    float S = 0.f;
    size_t base = ((size_t)bh << 17) + ij;
    for (int c = 0; c < NC_; ++c) {
        size_t idx = base + ((size_t)c << 12);
        float bv = BS[idx];
        float d = Dc[(size_t)(bh * NC_ + c) * 64 + i];
        BS[idx] = S;
        S = d * S + bv;
    }
}

// ---------------------------------------------------------------------------
// Phase C: o[tau][j] += rt[tau] . S_in[:, j]
__global__ __launch_bounds__(256) void scan_chunkC(const float* __restrict__ rt,
                                                   const float* __restrict__ BS,
                                                   float* o) {
    __shared__ float sS[64][64];
    __shared__ float sRt[CC_][68];
    int bid = blockIdx.x;
    int bh = bid >> 5, c = bid & (NC_ - 1);
    int b = bh >> 4, h = bh & 15;
    int tid = threadIdx.x;
    size_t sbase = ((size_t)bid) << 12;
    for (int q = tid; q < 1024; q += 256)
        *(float4*)&sS[q >> 4][(q & 15) << 2] = *(const float4*)&BS[sbase + (q << 2)];
    size_t base = ((size_t)(b * T_ + c * CC_)) * KD_ + h * 64;
    for (int q = tid; q < CC_ * 16; q += 256) {
        int row = q >> 4, col4 = (q & 15) << 2;
        *(float4*)&sRt[row][col4] = *(const float4*)&rt[base + (size_t)row * KD_ + col4];
    }
    __syncthreads();
    int tau = tid >> 3, j0 = (tid & 7) * 8;
    size_t obase = base + (size_t)tau * KD_ + j0;
    float acc[8] __attribute__((aligned(16)));
    *(float4*)&acc[0] = *(const float4*)&o[obase];
    *(float4*)&acc[4] = *(const float4*)&o[obase + 4];
    for (int i = 0; i < 64; ++i) {
        float a = sRt[tau][i];
        #pragma unroll
        for (int q = 0; q < 8; ++q) acc[q] += a * sS[i][j0 + q];
    }
    *(float4*)&o[obase]     = *(float4*)&acc[0];
    *(float4*)&o[obase + 4] = *(float4*)&acc[4];
}

// ---------------------------------------------------------------------------
// Per-head layernorm + swish gate. One wave per (b,t,h) row of 64.
__global__ __launch_bounds__(256) void lngate_kernel(const float* __restrict__ o,
                                                     const float* __restrict__ g,
                                                     const float* __restrict__ lw,
                                                     const float* __restrict__ lb,
                                                     float* __restrict__ out) {
    int row = blockIdx.x * 4 + (threadIdx.x >> 6);
    int c = threadIdx.x & 63;
    size_t idx = (size_t)row * 64 + c;
    float oc = o[idx];
    float s = oc;
    #pragma unroll
    for (int m = 32; m >= 1; m >>= 1) s += __shfl_xor(s, m, 64);
    float mean = s * (1.f / 64.f);
    float dx = oc - mean;
    float s2 = dx * dx;
    #pragma unroll
    for (int m = 32; m >= 1; m >>= 1) s2 += __shfl_xor(s2, m, 64);
    float var = s2 * (1.f / 64.f);
    float on = dx * rsqrtf(var + 1e-5f) * lw[c] + lb[c];
    float gv = g[idx];
    out[idx] = on * gv / (1.f + expf(-gv));
}

// ---------------------------------------------------------------------------
extern "C" void kernel_launch(void* const* d_in, const int* in_sizes, int n_in,
                              void* d_out, int out_size, void* d_ws, size_t ws_size,
                              hipStream_t stream) {
    const float* x     = (const float*)d_in[0];
    const float* mu_x  = (const float*)d_in[1];
    const float* Wx1   = (const float*)d_in[2];
    const float* Wx2   = (const float*)d_in[3];
    const float* xbias = (const float*)d_in[4];
    const float* Wr    = (const float*)d_in[5];
    const float* Wk    = (const float*)d_in[6];
    const float* Wv    = (const float*)d_in[7];
    const float* Ww_a  = (const float*)d_in[8];
    const float* Ww_b  = (const float*)d_in[9];
    const float* bw    = (const float*)d_in[10];
    const float* Wg_a  = (const float*)d_in[11];
    const float* Wg_b  = (const float*)d_in[12];
    const float* bg    = (const float*)d_in[13];
    const float* bonus = (const float*)d_in[14];
    const float* ln_w  = (const float*)d_in[15];
    const float* ln_b  = (const float*)d_in[16];
    const float* Wo    = (const float*)d_in[17];
    float* out = (float*)d_out;

    // workspace layout (floats), ~84 MB total
    float* ws  = (float*)d_ws;
    float* xm  = ws;                                // M_*H_  (16 MB)
    float* lr  = xm  + (size_t)M_ * H_;             // M_*320
    float* hid = lr  + (size_t)M_ * 320;            // M_*64
    float* rb  = hid + (size_t)M_ * 64;             // M_*KD_
    float* kb  = rb  + (size_t)M_ * KD_;
    float* vb  = kb  + (size_t)M_ * KD_;
    float* db  = vb  + (size_t)M_ * KD_;            // log-decay
    float* gb  = db  + (size_t)M_ * KD_;            // raw gate
    float* ob  = gb  + (size_t)M_ * KD_;            // o_intra then final o
    float* BS  = ob  + (size_t)M_ * KD_;            // 1024*64*64
    float* Dc  = BS  + (size_t)1024 * 4096;         // 1024*64
    float* gated = xm;                              // reuse xm after branches done

    const int elems = M_ * H_;
    dim3 blk(256);
    dim3 musgrid(H_ / 64, M_ / 64);

    // 1. lr = tanh((x + delta*mu_x) @ Wx1)
    mix_mu_kernel<<<elems / 256, blk, 0, stream>>>(x, mu_x, xm);
    gemm_f32<1><<<dim3(320 / 64, M_ / 64), blk, 0, stream>>>(xm, Wx1, nullptr, lr,
                                                             H_, H_, 320, 320);
    // 2. branch r
    musgemm_kernel<<<musgrid, blk, 0, stream>>>(x, lr, Wx2, xbias, xm, 0);
    gemm_f32<0><<<dim3(KD_ / 64, M_ / 64), blk, 0, stream>>>(xm, Wr, nullptr, rb,
                                                             H_, H_, KD_, KD_);
    // 3. branch w: log-decay = -exp(tanh(xm@Ww_a)@Ww_b + bw)
    musgemm_kernel<<<musgrid, blk, 0, stream>>>(x, lr, Wx2, xbias, xm, 1);
    gemm_f32<1><<<dim3(1, M_ / 64), blk, 0, stream>>>(xm, Ww_a, nullptr, hid,
                                                      H_, H_, 64, 64);
    gemm_f32<3><<<dim3(KD_ / 64, M_ / 64), blk, 0, stream>>>(hid, Ww_b, bw, db,
                                                             64, 64, KD_, KD_);
    // 4. branch k
    musgemm_kernel<<<musgrid, blk, 0, stream>>>(x, lr, Wx2, xbias, xm, 2);
    gemm_f32<0><<<dim3(KD_ / 64, M_ / 64), blk, 0, stream>>>(xm, Wk, nullptr, kb,
                                                             H_, H_, KD_, KD_);
    // 5. branch v
    musgemm_kernel<<<musgrid, blk, 0, stream>>>(x, lr, Wx2, xbias, xm, 3);
    gemm_f32<0><<<dim3(KD_ / 64, M_ / 64), blk, 0, stream>>>(xm, Wv, nullptr, vb,
                                                             H_, H_, KD_, KD_);
    // 6. branch g
    musgemm_kernel<<<musgrid, blk, 0, stream>>>(x, lr, Wx2, xbias, xm, 4);
    gemm_f32<1><<<dim3(1, M_ / 64), blk, 0, stream>>>(xm, Wg_a, nullptr, hid,
                                                      H_, H_, 64, 64);
    gemm_f32<2><<<dim3(KD_ / 64, M_ / 64), blk, 0, stream>>>(hid, Wg_b, bg, gb,
                                                             64, 64, KD_, KD_);

    // 7. chunk-parallel scan
    scan_chunkA<<<B_ * NH_ * NC_, blk, 0, stream>>>(rb, kb, vb, db, bonus,
                                                    rb /*rt in place*/, ob, BS, Dc);
    scan_chunkB<<<(B_ * NH_ * 4096) / 256, blk, 0, stream>>>(BS, Dc);
    scan_chunkC<<<B_ * NH_ * NC_, blk, 0, stream>>>(rb, BS, ob);

    // 8. per-head LN + swish gate
    lngate_kernel<<<(M_ * NH_) / 4, blk, 0, stream>>>(ob, gb, ln_w, ln_b, gated);

    // 9. out = gated @ Wo
    gemm_f32<0><<<dim3(H_ / 64, M_ / 64), blk, 0, stream>>>(gated, Wo, nullptr, out,
                                                            KD_, KD_, H_, H_);
}

// Round 4
// 493.955 us; speedup vs baseline: 5.2750x; 1.8086x over previous
//
#include <hip/hip_runtime.h>
#include <hip/hip_bf16.h>

#define H_    2048
#define NH_   16
#define KD_   1024
#define DK_   64
#define T_    1024
#define B_    2
#define M_    (B_*T_)     // 2048 rows
#define RL_   64
#define CC_   32          // scan chunk length
#define NC_   (T_/CC_)    // 32 chunks per sequence

typedef short bf16x8 __attribute__((ext_vector_type(8)));   // 8 bf16 (4 VGPR)
typedef float f32x4  __attribute__((ext_vector_type(4)));   // MFMA acc

__device__ __forceinline__ ushort bf16r(float f) {          // RNE fp32->bf16
    union { float f; unsigned u; } v; v.f = f;
    return (ushort)((v.u + 0x7FFF + ((v.u >> 16) & 1)) >> 16);
}

// ---------------------------------------------------------------------------
// Tiled bf16 layouts:
//  A-tiles (BM=128, BK=32): tile id (rb*KB + kb), 4096 bf16/tile,
//    elem (r,k): off = (g*128 + r)*8 + (k&7),  g=(k>>3)&3
//  B-tiles (BN=64, BK=32): tile id (nb*KB + kb), 2048 bf16/tile,
//    elem (c,k): off = (g*64 + c)*8 + (k&7)
// ---------------------------------------------------------------------------

// xx = x + (shift(x)-x)*mu_x  -> tiled bf16 A-layout (chunk per thread)
__global__ __launch_bounds__(256) void mix_mu_t(const float* __restrict__ x,
                                                const float* __restrict__ mu,
                                                ushort* __restrict__ At) {
    int c = blockIdx.x * 256 + threadIdx.x;       // chunk id 0..M_*H_/8
    int bt = c >> 8, k8 = c & 255;
    int k = k8 << 3;
    int t = bt & (T_ - 1);
    const float* xp = &x[(size_t)bt * H_ + k];
    float4 xa = *(const float4*)xp;
    float4 xb = *(const float4*)(xp + 4);
    float4 sa = make_float4(0,0,0,0), sb = make_float4(0,0,0,0);
    if (t > 0) { sa = *(const float4*)(xp - H_); sb = *(const float4*)(xp - H_ + 4); }
    float4 ma = *(const float4*)&mu[k];
    float4 mb = *(const float4*)&mu[k + 4];
    ushort o[8];
    o[0] = bf16r(xa.x + (sa.x - xa.x) * ma.x);
    o[1] = bf16r(xa.y + (sa.y - xa.y) * ma.y);
    o[2] = bf16r(xa.z + (sa.z - xa.z) * ma.z);
    o[3] = bf16r(xa.w + (sa.w - xa.w) * ma.w);
    o[4] = bf16r(xb.x + (sb.x - xb.x) * mb.x);
    o[5] = bf16r(xb.y + (sb.y - xb.y) * mb.y);
    o[6] = bf16r(xb.z + (sb.z - xb.z) * mb.z);
    o[7] = bf16r(xb.w + (sb.w - xb.w) * mb.w);
    int rb = bt >> 7, kb = k8 >> 2, g = k8 & 3, r = bt & 127;
    *(uint4*)&At[(((size_t)(rb * 64 + kb)) << 12) + ((g << 7) + r) * 8] = *(uint4*)o;
}

// ---------------------------------------------------------------------------
// W [K][N] fp32 -> tiled bf16 B-layout (per 32x64 tile block, LDS transpose)
__global__ __launch_bounds__(256) void convert_w(const float* __restrict__ W,
                                                 ushort* __restrict__ Wt,
                                                 int K, int N) {
    __shared__ float s[32][68];
    int kb = blockIdx.y, nb = blockIdx.x;
    int t = threadIdx.x;
    #pragma unroll
    for (int i = 0; i < 2; ++i) {
        int q = t + i * 256;                       // 0..511 float4s
        int k = q >> 4, c4 = (q & 15) << 2;
        *(float4*)&s[k][c4] = *(const float4*)&W[(size_t)(kb * 32 + k) * N + nb * 64 + c4];
    }
    __syncthreads();
    int g = t >> 6, c = t & 63;
    ushort o[8];
    #pragma unroll
    for (int e = 0; e < 8; ++e) o[e] = bf16r(s[g * 8 + e][c]);
    *(uint4*)&Wt[((size_t)(nb * (K >> 5) + kb)) * 2048 + t * 8] = *(uint4*)o;
}

// ---------------------------------------------------------------------------
// bf16 MFMA GEMM: C[M][ldc] = epi(A @ B), A tiled bf16 (BM=128), B tiled (BN=64).
// 256 thr = 4 waves (2x2), wave = 64x32 out = 4x2 frags of 16x16, BK=32.
// EPI: 0 = none, 1 = tanh
template<int EPI>
__global__ __launch_bounds__(256) void gemm_bf16t(const ushort* __restrict__ At,
                                                  const ushort* __restrict__ Bt,
                                                  float* __restrict__ C,
                                                  int K, int ldc) {
    __shared__ ushort Alds[4096];
    __shared__ ushort Blds[2048];
    int tid = threadIdx.x;
    int w = tid >> 6, l = tid & 63;
    int KB = K >> 5;
    const ushort* Ag = At + (size_t)blockIdx.y * KB * 4096 + tid * 8;
    const ushort* Bg = Bt + (size_t)blockIdx.x * KB * 2048 + tid * 8;
    int wr = (w >> 1) << 6, wc = (w & 1) << 5;
    int a_off = (((l >> 4) << 7) + wr + (l & 15)) << 3;   // (g*128 + row)*8
    int b_off = (((l >> 4) << 6) + wc + (l & 15)) << 3;   // (g*64 + col)*8
    f32x4 acc[8] = {};
    uint4 a0 = *(const uint4*)(Ag);
    uint4 a1 = *(const uint4*)(Ag + 2048);
    uint4 b0 = *(const uint4*)(Bg);
    for (int kt = 0; kt < KB; ++kt) {
        __syncthreads();                       // prior ds_reads done
        *(uint4*)&Alds[tid * 8] = a0;
        *(uint4*)&Alds[tid * 8 + 2048] = a1;
        *(uint4*)&Blds[tid * 8] = b0;
        __syncthreads();
        if (kt + 1 < KB) {                     // prefetch next K-tile
            Ag += 4096; Bg += 2048;
            a0 = *(const uint4*)(Ag);
            a1 = *(const uint4*)(Ag + 2048);
            b0 = *(const uint4*)(Bg);
        }
        bf16x8 af0 = *(const bf16x8*)&Alds[a_off];
        bf16x8 af1 = *(const bf16x8*)&Alds[a_off + 128];
        bf16x8 af2 = *(const bf16x8*)&Alds[a_off + 256];
        bf16x8 af3 = *(const bf16x8*)&Alds[a_off + 384];
        bf16x8 bf0 = *(const bf16x8*)&Blds[b_off];
        bf16x8 bf1 = *(const bf16x8*)&Blds[b_off + 128];
        acc[0] = __builtin_amdgcn_mfma_f32_16x16x32_bf16(af0, bf0, acc[0], 0, 0, 0);
        acc[1] = __builtin_amdgcn_mfma_f32_16x16x32_bf16(af0, bf1, acc[1], 0, 0, 0);
        acc[2] = __builtin_amdgcn_mfma_f32_16x16x32_bf16(af1, bf0, acc[2], 0, 0, 0);
        acc[3] = __builtin_amdgcn_mfma_f32_16x16x32_bf16(af1, bf1, acc[3], 0, 0, 0);
        acc[4] = __builtin_amdgcn_mfma_f32_16x16x32_bf16(af2, bf0, acc[4], 0, 0, 0);
        acc[5] = __builtin_amdgcn_mfma_f32_16x16x32_bf16(af2, bf1, acc[5], 0, 0, 0);
        acc[6] = __builtin_amdgcn_mfma_f32_16x16x32_bf16(af3, bf0, acc[6], 0, 0, 0);
        acc[7] = __builtin_amdgcn_mfma_f32_16x16x32_bf16(af3, bf1, acc[7], 0, 0, 0);
    }
    int row0 = (blockIdx.y << 7) + wr + ((l >> 4) << 2);
    int col0 = (blockIdx.x << 6) + wc + (l & 15);
    #pragma unroll
    for (int fr = 0; fr < 4; ++fr)
        #pragma unroll
        for (int fc = 0; fc < 2; ++fc) {
            f32x4 v = acc[fr * 2 + fc];
            #pragma unroll
            for (int q = 0; q < 4; ++q) {
                float o = v[q];
                if (EPI == 1) o = tanhf(o);
                C[(size_t)(row0 + fr * 16 + q) * ldc + col0 + fc * 16] = o;
            }
        }
}

// ---------------------------------------------------------------------------
// Fused mus-GEMM + lerp. tiled=1: write bf16 A-tiled xmt; else fp32 xm.
__global__ __launch_bounds__(256) void musgemm_kernel(const float* __restrict__ x,
                                                      const float* __restrict__ lr,
                                                      const float* __restrict__ Wx2,
                                                      const float* __restrict__ xbias,
                                                      float* __restrict__ xm,
                                                      ushort* __restrict__ xmt,
                                                      int branch, int tiled) {
    __shared__ float sL[64][68];
    __shared__ float sW[64][68];
    int tid = threadIdx.x;
    int tx = tid & 15, ty = tid >> 4;
    int col0 = blockIdx.x * 64;    // h
    int row0 = blockIdx.y * 64;    // bt
    for (int q = tid; q < 1024; q += 256) {
        int r = q >> 4, k4 = (q & 15) << 2;
        *(float4*)&sL[r][k4] = *(const float4*)&lr[(size_t)(row0 + r) * 320 + branch * 64 + k4];
        *(float4*)&sW[r][k4] = *(const float4*)&Wx2[(size_t)(col0 + r) * 320 + branch * 64 + k4];
    }
    __syncthreads();
    float acc[4][4] = {};
    for (int k = 0; k < 64; k += 4) {
        float4 a[4], b[4];
        #pragma unroll
        for (int i = 0; i < 4; ++i) a[i] = *(const float4*)&sL[(ty << 2) + i][k];
        #pragma unroll
        for (int j = 0; j < 4; ++j) b[j] = *(const float4*)&sW[(tx << 2) + j][k];
        #pragma unroll
        for (int i = 0; i < 4; ++i)
            #pragma unroll
            for (int j = 0; j < 4; ++j)
                acc[i][j] += a[i].x * b[j].x + a[i].y * b[j].y
                           + a[i].z * b[j].z + a[i].w * b[j].w;
    }
    float4 bias4 = *(const float4*)&xbias[branch * H_ + col0 + (tx << 2)];
    float bb[4] = {bias4.x, bias4.y, bias4.z, bias4.w};
    int kcol = col0 + (tx << 2);
    #pragma unroll
    for (int i = 0; i < 4; ++i) {
        int r = row0 + (ty << 2) + i;
        int t = r & (T_ - 1);
        const float* xrow = &x[(size_t)r * H_ + kcol];
        float4 xv = *(const float4*)xrow;
        float4 sh = make_float4(0.f, 0.f, 0.f, 0.f);
        if (t > 0) sh = *(const float4*)(xrow - H_);
        float o0 = xv.x + (sh.x - xv.x) * (acc[i][0] + bb[0]);
        float o1 = xv.y + (sh.y - xv.y) * (acc[i][1] + bb[1]);
        float o2 = xv.z + (sh.z - xv.z) * (acc[i][2] + bb[2]);
        float o3 = xv.w + (sh.w - xv.w) * (acc[i][3] + bb[3]);
        if (tiled) {
            int rb = r >> 7, kb = kcol >> 5, g = (kcol >> 3) & 3, hf = (kcol >> 2) & 1;
            ushort4 pk; pk.x = bf16r(o0); pk.y = bf16r(o1); pk.z = bf16r(o2); pk.w = bf16r(o3);
            *(ushort4*)&xmt[(((size_t)(rb * 64 + kb)) << 12) + ((g << 7) + (r & 127)) * 8 + hf * 4] = pk;
        } else {
            float4 o; o.x = o0; o.y = o1; o.z = o2; o.w = o3;
            *(float4*)&xm[(size_t)r * H_ + kcol] = o;
        }
    }
}

// ---------------------------------------------------------------------------
// fp32 GEMM (kept for LoRA paths). EPI: 1 = tanh, 2 = +bias, 3 = -exp(v+bias)
template<int EPI>
__global__ __launch_bounds__(256) void gemm_f32(const float* __restrict__ A,
                                                const float* __restrict__ W,
                                                const float* __restrict__ bias,
                                                float* __restrict__ C,
                                                int K, int lda, int ldb, int ldc) {
    __shared__ float As[16][68];
    __shared__ float Bs[16][68];
    int tid = threadIdx.x;
    int tx = tid & 15, ty = tid >> 4;
    int row0 = blockIdx.y * 64, col0 = blockIdx.x * 64;
    int am = tid >> 2, ak = (tid & 3) << 2;
    int bk = tid >> 4, bn = (tid & 15) << 2;
    float acc[4][4] = {};
    float4 av = *(const float4*)&A[(size_t)(row0 + am) * lda + ak];
    float4 bv = *(const float4*)&W[(size_t)bk * ldb + col0 + bn];
    for (int k0 = 0; k0 < K; k0 += 16) {
        __syncthreads();
        As[ak + 0][am] = av.x; As[ak + 1][am] = av.y;
        As[ak + 2][am] = av.z; As[ak + 3][am] = av.w;
        *(float4*)&Bs[bk][bn] = bv;
        __syncthreads();
        if (k0 + 16 < K) {
            av = *(const float4*)&A[(size_t)(row0 + am) * lda + k0 + 16 + ak];
            bv = *(const float4*)&W[(size_t)(k0 + 16 + bk) * ldb + col0 + bn];
        }
        #pragma unroll
        for (int kk = 0; kk < 16; ++kk) {
            float4 a = *(const float4*)&As[kk][ty << 2];
            float4 b = *(const float4*)&Bs[kk][tx << 2];
            float aa[4] = {a.x, a.y, a.z, a.w};
            float bb[4] = {b.x, b.y, b.z, b.w};
            #pragma unroll
            for (int i = 0; i < 4; ++i)
                #pragma unroll
                for (int j = 0; j < 4; ++j)
                    acc[i][j] = fmaf(aa[i], bb[j], acc[i][j]);
        }
    }
    #pragma unroll
    for (int i = 0; i < 4; ++i) {
        int r = row0 + (ty << 2) + i;
        #pragma unroll
        for (int j = 0; j < 4; ++j) {
            int c = col0 + (tx << 2) + j;
            float v = acc[i][j];
            if (EPI == 2 || EPI == 3) v += bias[c];
            if (EPI == 1) v = tanhf(v);
            if (EPI == 3) v = -expf(v);   // store LOG decay
            C[(size_t)r * ldc + c] = v;
        }
    }
}

// ---------------------------------------------------------------------------
// Chunked scan, phase A (unchanged).
__global__ __launch_bounds__(256) void scan_chunkA(const float* r, const float* k,
                                                   const float* v, const float* ld,
                                                   const float* u,
                                                   float* rt, float* ointra,
                                                   float* Bc, float* Dc) {
    __shared__ float sR[CC_][68], sK[CC_][68], sV[CC_][68], sW[CC_][68];
    __shared__ float wc[CC_ + 1][64];
    __shared__ float sA[CC_][36];
    __shared__ float diag[CC_];
    __shared__ float sU[64];
    int bid = blockIdx.x;
    int bh = bid >> 5, c = bid & (NC_ - 1);
    int b = bh >> 4, h = bh & 15;
    int tid = threadIdx.x;
    size_t base = ((size_t)(b * T_ + c * CC_)) * KD_ + h * 64;

    for (int q = tid; q < CC_ * 16; q += 256) {
        int row = q >> 4, col4 = (q & 15) << 2;
        size_t gi = base + (size_t)row * KD_ + col4;
        *(float4*)&sR[row][col4] = *(const float4*)&r[gi];
        *(float4*)&sK[row][col4] = *(const float4*)&k[gi];
        *(float4*)&sV[row][col4] = *(const float4*)&v[gi];
        *(float4*)&sW[row][col4] = *(const float4*)&ld[gi];
    }
    if (tid < 64) sU[tid] = u[h * 64 + tid];
    __syncthreads();

    if (tid < 64) {
        float acc = 0.f;
        wc[0][tid] = 0.f;
        #pragma unroll
        for (int s = 0; s < CC_; ++s) { acc += sW[s][tid]; wc[s + 1][tid] = acc; }
    }
    {
        int tau = tid >> 3, g = tid & 7;
        float p = 0.f;
        #pragma unroll
        for (int q = 0; q < 8; ++q) {
            int i = g * 8 + q;
            p += sR[tau][i] * sU[i] * sK[tau][i];
        }
        p += __shfl_xor(p, 1, 64); p += __shfl_xor(p, 2, 64); p += __shfl_xor(p, 4, 64);
        if (g == 0) diag[tau] = p;
    }
    __syncthreads();

    for (int q = tid; q < CC_ * 64; q += 256) {
        int s = q >> 6, i = q & 63;
        float wcs  = wc[s][i];
        float wcs1 = wc[s + 1][i];
        float wcc  = wc[CC_][i];
        float rt_ = sR[s][i] * expf(wcs);
        float kt_ = sK[s][i] * expf(-wcs1);
        float bb  = sK[s][i] * expf(wcc - wcs1);
        sR[s][i] = rt_;
        sW[s][i] = kt_;
        sK[s][i] = bb;
        rt[base + (size_t)s * KD_ + i] = rt_;
    }
    if (tid < 64) Dc[(size_t)bid * 64 + tid] = expf(wc[CC_][tid]);
    __syncthreads();

    {
        int tau = tid >> 3, s0 = (tid & 7) * 4;
        float a0 = 0, a1 = 0, a2 = 0, a3 = 0;
        for (int i = 0; i < 64; i += 4) {
            float4 rr = *(const float4*)&sR[tau][i];
            float4 k0v = *(const float4*)&sW[s0 + 0][i];
            float4 k1v = *(const float4*)&sW[s0 + 1][i];
            float4 k2v = *(const float4*)&sW[s0 + 2][i];
            float4 k3v = *(const float4*)&sW[s0 + 3][i];
            a0 += rr.x * k0v.x + rr.y * k0v.y + rr.z * k0v.z + rr.w * k0v.w;
            a1 += rr.x * k1v.x + rr.y * k1v.y + rr.z * k1v.z + rr.w * k1v.w;
            a2 += rr.x * k2v.x + rr.y * k2v.y + rr.z * k2v.z + rr.w * k2v.w;
            a3 += rr.x * k3v.x + rr.y * k3v.y + rr.z * k3v.z + rr.w * k3v.w;
        }
        sA[tau][s0 + 0] = (s0 + 0 < tau) ? a0 : ((s0 + 0 == tau) ? diag[tau] : 0.f);
        sA[tau][s0 + 1] = (s0 + 1 < tau) ? a1 : ((s0 + 1 == tau) ? diag[tau] : 0.f);
        sA[tau][s0 + 2] = (s0 + 2 < tau) ? a2 : ((s0 + 2 == tau) ? diag[tau] : 0.f);
        sA[tau][s0 + 3] = (s0 + 3 < tau) ? a3 : ((s0 + 3 == tau) ? diag[tau] : 0.f);
    }
    __syncthreads();

    {
        int tau = tid >> 3, j0 = (tid & 7) * 8;
        float o_[8] __attribute__((aligned(16))) = {};
        for (int s = 0; s < CC_; ++s) {
            float a = sA[tau][s];
            #pragma unroll
            for (int q = 0; q < 8; ++q) o_[q] += a * sV[s][j0 + q];
        }
        size_t ob = base + (size_t)tau * KD_ + j0;
        *(float4*)&ointra[ob]     = *(float4*)&o_[0];
        *(float4*)&ointra[ob + 4] = *(float4*)&o_[4];
    }
    {
        int i = tid >> 2, j0 = (tid & 3) * 16;
        float bacc[16] __attribute__((aligned(16))) = {};
        for (int s = 0; s < CC_; ++s) {
            float bi = sK[s][i];
            #pragma unroll
            for (int q = 0; q < 16; ++q) bacc[q] += bi * sV[s][j0 + q];
        }
        size_t bb = ((size_t)bid << 12) + i * 64 + j0;
        *(float4*)&Bc[bb + 0]  = *(float4*)&bacc[0];
        *(float4*)&Bc[bb + 4]  = *(float4*)&bacc[4];
        *(float4*)&Bc[bb + 8]  = *(float4*)&bacc[8];
        *(float4*)&Bc[bb + 12] = *(float4*)&bacc[12];
    }
}

// ---------------------------------------------------------------------------
__global__ __launch_bounds__(256) void scan_chunkB(float* BS, const float* __restrict__ Dc) {
    int g = blockIdx.x * 256 + threadIdx.x;
    int bh = g >> 12, ij = g & 4095, i = ij >> 6;
    float S = 0.f;
    size_t base = ((size_t)bh << 17) + ij;
    for (int c = 0; c < NC_; ++c) {
        size_t idx = base + ((size_t)c << 12);
        float bv = BS[idx];
        float d = Dc[(size_t)(bh * NC_ + c) * 64 + i];
        BS[idx] = S;
        S = d * S + bv;
    }
}

// ---------------------------------------------------------------------------
__global__ __launch_bounds__(256) void scan_chunkC(const float* __restrict__ rt,
                                                   const float* __restrict__ BS,
                                                   float* o) {
    __shared__ float sS[64][64];
    __shared__ float sRt[CC_][68];
    int bid = blockIdx.x;
    int bh = bid >> 5, c = bid & (NC_ - 1);
    int b = bh >> 4, h = bh & 15;
    int tid = threadIdx.x;
    size_t sbase = ((size_t)bid) << 12;
    for (int q = tid; q < 1024; q += 256)
        *(float4*)&sS[q >> 4][(q & 15) << 2] = *(const float4*)&BS[sbase + (q << 2)];
    size_t base = ((size_t)(b * T_ + c * CC_)) * KD_ + h * 64;
    for (int q = tid; q < CC_ * 16; q += 256) {
        int row = q >> 4, col4 = (q & 15) << 2;
        *(float4*)&sRt[row][col4] = *(const float4*)&rt[base + (size_t)row * KD_ + col4];
    }
    __syncthreads();
    int tau = tid >> 3, j0 = (tid & 7) * 8;
    size_t obase = base + (size_t)tau * KD_ + j0;
    float acc[8] __attribute__((aligned(16)));
    *(float4*)&acc[0] = *(const float4*)&o[obase];
    *(float4*)&acc[4] = *(const float4*)&o[obase + 4];
    for (int i = 0; i < 64; ++i) {
        float a = sRt[tau][i];
        #pragma unroll
        for (int q = 0; q < 8; ++q) acc[q] += a * sS[i][j0 + q];
    }
    *(float4*)&o[obase]     = *(float4*)&acc[0];
    *(float4*)&o[obase + 4] = *(float4*)&acc[4];
}

// ---------------------------------------------------------------------------
// Per-head LN + swish gate -> tiled bf16 A-layout (K=1024, KB=32)
__global__ __launch_bounds__(256) void lngate_kernel(const float* __restrict__ o,
                                                     const float* __restrict__ g,
                                                     const float* __restrict__ lw,
                                                     const float* __restrict__ lb,
                                                     ushort* __restrict__ outt) {
    int rr = blockIdx.x * 4 + (threadIdx.x >> 6);   // (bt*16 + h)
    int c = threadIdx.x & 63;
    size_t idx = (size_t)rr * 64 + c;
    float oc = o[idx];
    float s = oc;
    #pragma unroll
    for (int m = 32; m >= 1; m >>= 1) s += __shfl_xor(s, m, 64);
    float mean = s * (1.f / 64.f);
    float dx = oc - mean;
    float s2 = dx * dx;
    #pragma unroll
    for (int m = 32; m >= 1; m >>= 1) s2 += __shfl_xor(s2, m, 64);
    float var = s2 * (1.f / 64.f);
    float on = dx * rsqrtf(var + 1e-5f) * lw[c] + lb[c];
    float gv = g[idx];
    float val = on * gv / (1.f + expf(-gv));
    int mrow = rr >> 4;
    int col = ((rr & 15) << 6) + c;
    int rb = mrow >> 7, kb = col >> 5, gg = (col >> 3) & 3;
    outt[(((size_t)(rb * 32 + kb)) << 12) + ((gg << 7) + (mrow & 127)) * 8 + (col & 7)] = bf16r(val);
}

// ---------------------------------------------------------------------------
extern "C" void kernel_launch(void* const* d_in, const int* in_sizes, int n_in,
                              void* d_out, int out_size, void* d_ws, size_t ws_size,
                              hipStream_t stream) {
    const float* x     = (const float*)d_in[0];
    const float* mu_x  = (const float*)d_in[1];
    const float* Wx1   = (const float*)d_in[2];
    const float* Wx2   = (const float*)d_in[3];
    const float* xbias = (const float*)d_in[4];
    const float* Wr    = (const float*)d_in[5];
    const float* Wk    = (const float*)d_in[6];
    const float* Wv    = (const float*)d_in[7];
    const float* Ww_a  = (const float*)d_in[8];
    const float* Ww_b  = (const float*)d_in[9];
    const float* bw    = (const float*)d_in[10];
    const float* Wg_a  = (const float*)d_in[11];
    const float* Wg_b  = (const float*)d_in[12];
    const float* bg    = (const float*)d_in[13];
    const float* bonus = (const float*)d_in[14];
    const float* ln_w  = (const float*)d_in[15];
    const float* ln_b  = (const float*)d_in[16];
    const float* Wo    = (const float*)d_in[17];
    float* out = (float*)d_out;

    // workspace layout (float units)
    float* ws  = (float*)d_ws;
    float* xm  = ws;                                // M_*H_ fp32 (branches w,g)
    float* lr  = xm  + (size_t)M_ * H_;             // M_*320
    float* hid = lr  + (size_t)M_ * 320;            // M_*64
    float* rb_ = hid + (size_t)M_ * 64;             // M_*KD_
    float* kb_ = rb_ + (size_t)M_ * KD_;
    float* vb_ = kb_ + (size_t)M_ * KD_;
    float* db_ = vb_ + (size_t)M_ * KD_;            // log-decay
    float* gb_ = db_ + (size_t)M_ * KD_;            // raw gate
    float* ob_ = gb_ + (size_t)M_ * KD_;            // o_intra then final o
    float* BS  = ob_ + (size_t)M_ * KD_;            // 1024*4096
    float* Dc  = BS  + (size_t)1024 * 4096;         // 1024*64
    float* wend = Dc + (size_t)1024 * 64;
    // bf16 regions (ushort units)
    ushort* xmt  = (ushort*)xm;                     // overlay: tiled bf16 xm (8 MB)
    ushort* gt   = (ushort*)(xm + (size_t)M_ * H_ / 2);  // tiled gated (4 MB), after xmt
    ushort* Wx1t = (ushort*)wend;                   // 2048*320
    ushort* Wrt  = Wx1t + (size_t)H_ * 320;
    ushort* Wkt  = Wrt  + (size_t)H_ * KD_;
    ushort* Wvt  = Wkt  + (size_t)H_ * KD_;
    ushort* Wot  = Wvt  + (size_t)H_ * KD_;         // 1024*2048

    dim3 blk(256);
    const int elems8 = M_ * H_ / 8;

    // 0. weight conversions (tiled bf16)
    convert_w<<<dim3(320 / 64, H_ / 32), blk, 0, stream>>>(Wx1, Wx1t, H_, 320);
    convert_w<<<dim3(KD_ / 64, H_ / 32), blk, 0, stream>>>(Wr, Wrt, H_, KD_);
    convert_w<<<dim3(KD_ / 64, H_ / 32), blk, 0, stream>>>(Wk, Wkt, H_, KD_);
    convert_w<<<dim3(KD_ / 64, H_ / 32), blk, 0, stream>>>(Wv, Wvt, H_, KD_);
    convert_w<<<dim3(H_ / 64, KD_ / 32), blk, 0, stream>>>(Wo, Wot, KD_, H_);

    // 1. lr = tanh((x + delta*mu_x) @ Wx1)   [bf16 MFMA]
    mix_mu_t<<<elems8 / 256, blk, 0, stream>>>(x, mu_x, xmt);
    gemm_bf16t<1><<<dim3(320 / 64, M_ / 128), blk, 0, stream>>>(xmt, Wx1t, lr, H_, 320);

    // 2. branch r  [bf16 MFMA]
    musgemm_kernel<<<dim3(H_ / 64, M_ / 64), blk, 0, stream>>>(x, lr, Wx2, xbias, nullptr, xmt, 0, 1);
    gemm_bf16t<0><<<dim3(KD_ / 64, M_ / 128), blk, 0, stream>>>(xmt, Wrt, rb_, H_, KD_);

    // 3. branch w (decay path stays fp32)
    musgemm_kernel<<<dim3(H_ / 64, M_ / 64), blk, 0, stream>>>(x, lr, Wx2, xbias, xm, nullptr, 1, 0);
    gemm_f32<1><<<dim3(1, M_ / 64), blk, 0, stream>>>(xm, Ww_a, nullptr, hid, H_, H_, 64, 64);
    gemm_f32<3><<<dim3(KD_ / 64, M_ / 64), blk, 0, stream>>>(hid, Ww_b, bw, db_, 64, 64, KD_, KD_);

    // 4. branch k  [bf16 MFMA]
    musgemm_kernel<<<dim3(H_ / 64, M_ / 64), blk, 0, stream>>>(x, lr, Wx2, xbias, nullptr, xmt, 2, 1);
    gemm_bf16t<0><<<dim3(KD_ / 64, M_ / 128), blk, 0, stream>>>(xmt, Wkt, kb_, H_, KD_);

    // 5. branch v  [bf16 MFMA]
    musgemm_kernel<<<dim3(H_ / 64, M_ / 64), blk, 0, stream>>>(x, lr, Wx2, xbias, nullptr, xmt, 3, 1);
    gemm_bf16t<0><<<dim3(KD_ / 64, M_ / 128), blk, 0, stream>>>(xmt, Wvt, vb_, H_, KD_);

    // 6. branch g (gate path stays fp32)
    musgemm_kernel<<<dim3(H_ / 64, M_ / 64), blk, 0, stream>>>(x, lr, Wx2, xbias, xm, nullptr, 4, 0);
    gemm_f32<1><<<dim3(1, M_ / 64), blk, 0, stream>>>(xm, Wg_a, nullptr, hid, H_, H_, 64, 64);
    gemm_f32<2><<<dim3(KD_ / 64, M_ / 64), blk, 0, stream>>>(hid, Wg_b, bg, gb_, 64, 64, KD_, KD_);

    // 7. chunk-parallel scan (fp32)
    scan_chunkA<<<B_ * NH_ * NC_, blk, 0, stream>>>(rb_, kb_, vb_, db_, bonus,
                                                    rb_ /*rt in place*/, ob_, BS, Dc);
    scan_chunkB<<<(B_ * NH_ * 4096) / 256, blk, 0, stream>>>(BS, Dc);
    scan_chunkC<<<B_ * NH_ * NC_, blk, 0, stream>>>(rb_, BS, ob_);

    // 8. LN + swish gate -> tiled bf16
    lngate_kernel<<<(M_ * NH_) / 4, blk, 0, stream>>>(ob_, gb_, ln_w, ln_b, gt);

    // 9. out = gated @ Wo  [bf16 MFMA]
    gemm_bf16t<0><<<dim3(H_ / 64, M_ / 128), blk, 0, stream>>>(gt, Wot, out, KD_, H_);
}

// Round 5
// 368.054 us; speedup vs baseline: 7.0795x; 1.3421x over previous
//
#include <hip/hip_runtime.h>
#include <hip/hip_bf16.h>

#define H_    2048
#define NH_   16
#define KD_   1024
#define DK_   64
#define T_    1024
#define B_    2
#define M_    (B_*T_)     // 2048 rows
#define RL_   64
#define CC_   32          // scan chunk length
#define NC_   (T_/CC_)    // 32 chunks per sequence

typedef short bf16x8 __attribute__((ext_vector_type(8)));   // 8 bf16 (4 VGPR)
typedef float f32x4  __attribute__((ext_vector_type(4)));   // MFMA acc

__device__ __forceinline__ ushort bf16r(float f) {          // RNE fp32->bf16
    union { float f; unsigned u; } v; v.f = f;
    return (ushort)((v.u + 0x7FFF + ((v.u >> 16) & 1)) >> 16);
}

// ---------------------------------------------------------------------------
// Tiled bf16 layouts:
//  A-tiles (BM=128, BK=32): tile id (rb*KB + kb), 4096 bf16/tile,
//    elem (r,k): off = (g*128 + r)*8 + (k&7),  g=(k>>3)&3
//  B-tiles (BN=64, BK=32): tile id (nb*KB + kb), 2048 bf16/tile,
//    elem (c,k): off = (g*64 + c)*8 + (k&7)
// ---------------------------------------------------------------------------

// xx = x + (shift(x)-x)*mu_x  -> tiled bf16 A-layout (chunk per thread)
__global__ __launch_bounds__(256) void mix_mu_t(const float* __restrict__ x,
                                                const float* __restrict__ mu,
                                                ushort* __restrict__ At) {
    int c = blockIdx.x * 256 + threadIdx.x;       // chunk id 0..M_*H_/8
    int bt = c >> 8, k8 = c & 255;
    int k = k8 << 3;
    int t = bt & (T_ - 1);
    const float* xp = &x[(size_t)bt * H_ + k];
    float4 xa = *(const float4*)xp;
    float4 xb = *(const float4*)(xp + 4);
    float4 sa = make_float4(0,0,0,0), sb = make_float4(0,0,0,0);
    if (t > 0) { sa = *(const float4*)(xp - H_); sb = *(const float4*)(xp - H_ + 4); }
    float4 ma = *(const float4*)&mu[k];
    float4 mb = *(const float4*)&mu[k + 4];
    ushort o[8];
    o[0] = bf16r(xa.x + (sa.x - xa.x) * ma.x);
    o[1] = bf16r(xa.y + (sa.y - xa.y) * ma.y);
    o[2] = bf16r(xa.z + (sa.z - xa.z) * ma.z);
    o[3] = bf16r(xa.w + (sa.w - xa.w) * ma.w);
    o[4] = bf16r(xb.x + (sb.x - xb.x) * mb.x);
    o[5] = bf16r(xb.y + (sb.y - xb.y) * mb.y);
    o[6] = bf16r(xb.z + (sb.z - xb.z) * mb.z);
    o[7] = bf16r(xb.w + (sb.w - xb.w) * mb.w);
    int rb = bt >> 7, kb = k8 >> 2, g = k8 & 3, r = bt & 127;
    *(uint4*)&At[(((size_t)(rb * 64 + kb)) << 12) + ((g << 7) + r) * 8] = *(uint4*)o;
}

// ---------------------------------------------------------------------------
// W [K][N] fp32 -> tiled bf16 B-layout (per 32x64 tile block, LDS transpose)
__global__ __launch_bounds__(256) void convert_w(const float* __restrict__ W,
                                                 ushort* __restrict__ Wt,
                                                 int K, int N) {
    __shared__ float s[32][68];
    int kb = blockIdx.y, nb = blockIdx.x;
    int t = threadIdx.x;
    #pragma unroll
    for (int i = 0; i < 2; ++i) {
        int q = t + i * 256;                       // 0..511 float4s
        int k = q >> 4, c4 = (q & 15) << 2;
        *(float4*)&s[k][c4] = *(const float4*)&W[(size_t)(kb * 32 + k) * N + nb * 64 + c4];
    }
    __syncthreads();
    int g = t >> 6, c = t & 63;
    ushort o[8];
    #pragma unroll
    for (int e = 0; e < 8; ++e) o[e] = bf16r(s[g * 8 + e][c]);
    *(uint4*)&Wt[((size_t)(nb * (K >> 5) + kb)) * 2048 + t * 8] = *(uint4*)o;
}

// ---------------------------------------------------------------------------
// bf16 MFMA GEMM: C[M][ldc] = epi(A @ B), A tiled bf16 (BM=128), B tiled (BN=64).
// 256 thr = 4 waves (2x2), wave = 64x32 out = 4x2 frags of 16x16, BK=32.
// EPI: 0 = none, 1 = tanh
template<int EPI>
__global__ __launch_bounds__(256) void gemm_bf16t(const ushort* __restrict__ At,
                                                  const ushort* __restrict__ Bt,
                                                  float* __restrict__ C,
                                                  int K, int ldc) {
    __shared__ ushort Alds[4096];
    __shared__ ushort Blds[2048];
    int tid = threadIdx.x;
    int w = tid >> 6, l = tid & 63;
    int KB = K >> 5;
    const ushort* Ag = At + (size_t)blockIdx.y * KB * 4096 + tid * 8;
    const ushort* Bg = Bt + (size_t)blockIdx.x * KB * 2048 + tid * 8;
    int wr = (w >> 1) << 6, wc = (w & 1) << 5;
    int a_off = (((l >> 4) << 7) + wr + (l & 15)) << 3;   // (g*128 + row)*8
    int b_off = (((l >> 4) << 6) + wc + (l & 15)) << 3;   // (g*64 + col)*8
    f32x4 acc[8] = {};
    uint4 a0 = *(const uint4*)(Ag);
    uint4 a1 = *(const uint4*)(Ag + 2048);
    uint4 b0 = *(const uint4*)(Bg);
    for (int kt = 0; kt < KB; ++kt) {
        __syncthreads();                       // prior ds_reads done
        *(uint4*)&Alds[tid * 8] = a0;
        *(uint4*)&Alds[tid * 8 + 2048] = a1;
        *(uint4*)&Blds[tid * 8] = b0;
        __syncthreads();
        if (kt + 1 < KB) {                     // prefetch next K-tile
            Ag += 4096; Bg += 2048;
            a0 = *(const uint4*)(Ag);
            a1 = *(const uint4*)(Ag + 2048);
            b0 = *(const uint4*)(Bg);
        }
        bf16x8 af0 = *(const bf16x8*)&Alds[a_off];
        bf16x8 af1 = *(const bf16x8*)&Alds[a_off + 128];
        bf16x8 af2 = *(const bf16x8*)&Alds[a_off + 256];
        bf16x8 af3 = *(const bf16x8*)&Alds[a_off + 384];
        bf16x8 bf0 = *(const bf16x8*)&Blds[b_off];
        bf16x8 bf1 = *(const bf16x8*)&Blds[b_off + 128];
        acc[0] = __builtin_amdgcn_mfma_f32_16x16x32_bf16(af0, bf0, acc[0], 0, 0, 0);
        acc[1] = __builtin_amdgcn_mfma_f32_16x16x32_bf16(af0, bf1, acc[1], 0, 0, 0);
        acc[2] = __builtin_amdgcn_mfma_f32_16x16x32_bf16(af1, bf0, acc[2], 0, 0, 0);
        acc[3] = __builtin_amdgcn_mfma_f32_16x16x32_bf16(af1, bf1, acc[3], 0, 0, 0);
        acc[4] = __builtin_amdgcn_mfma_f32_16x16x32_bf16(af2, bf0, acc[4], 0, 0, 0);
        acc[5] = __builtin_amdgcn_mfma_f32_16x16x32_bf16(af2, bf1, acc[5], 0, 0, 0);
        acc[6] = __builtin_amdgcn_mfma_f32_16x16x32_bf16(af3, bf0, acc[6], 0, 0, 0);
        acc[7] = __builtin_amdgcn_mfma_f32_16x16x32_bf16(af3, bf1, acc[7], 0, 0, 0);
    }
    int row0 = (blockIdx.y << 7) + wr + ((l >> 4) << 2);
    int col0 = (blockIdx.x << 6) + wc + (l & 15);
    #pragma unroll
    for (int fr = 0; fr < 4; ++fr)
        #pragma unroll
        for (int fc = 0; fc < 2; ++fc) {
            f32x4 v = acc[fr * 2 + fc];
            #pragma unroll
            for (int q = 0; q < 4; ++q) {
                float o = v[q];
                if (EPI == 1) o = tanhf(o);
                C[(size_t)(row0 + fr * 16 + q) * ldc + col0 + fc * 16] = o;
            }
        }
}

// ---------------------------------------------------------------------------
// Fused mus-GEMM + lerp. tiled=1: write bf16 A-tiled xmt; else fp32 xm.
__global__ __launch_bounds__(256) void musgemm_kernel(const float* __restrict__ x,
                                                      const float* __restrict__ lr,
                                                      const float* __restrict__ Wx2,
                                                      const float* __restrict__ xbias,
                                                      float* __restrict__ xm,
                                                      ushort* __restrict__ xmt,
                                                      int branch, int tiled) {
    __shared__ float sL[64][68];
    __shared__ float sW[64][68];
    int tid = threadIdx.x;
    int tx = tid & 15, ty = tid >> 4;
    int col0 = blockIdx.x * 64;    // h
    int row0 = blockIdx.y * 64;    // bt
    for (int q = tid; q < 1024; q += 256) {
        int r = q >> 4, k4 = (q & 15) << 2;
        *(float4*)&sL[r][k4] = *(const float4*)&lr[(size_t)(row0 + r) * 320 + branch * 64 + k4];
        *(float4*)&sW[r][k4] = *(const float4*)&Wx2[(size_t)(col0 + r) * 320 + branch * 64 + k4];
    }
    __syncthreads();
    float acc[4][4] = {};
    for (int k = 0; k < 64; k += 4) {
        float4 a[4], b[4];
        #pragma unroll
        for (int i = 0; i < 4; ++i) a[i] = *(const float4*)&sL[(ty << 2) + i][k];
        #pragma unroll
        for (int j = 0; j < 4; ++j) b[j] = *(const float4*)&sW[(tx << 2) + j][k];
        #pragma unroll
        for (int i = 0; i < 4; ++i)
            #pragma unroll
            for (int j = 0; j < 4; ++j)
                acc[i][j] += a[i].x * b[j].x + a[i].y * b[j].y
                           + a[i].z * b[j].z + a[i].w * b[j].w;
    }
    float4 bias4 = *(const float4*)&xbias[branch * H_ + col0 + (tx << 2)];
    float bb[4] = {bias4.x, bias4.y, bias4.z, bias4.w};
    int kcol = col0 + (tx << 2);
    #pragma unroll
    for (int i = 0; i < 4; ++i) {
        int r = row0 + (ty << 2) + i;
        int t = r & (T_ - 1);
        const float* xrow = &x[(size_t)r * H_ + kcol];
        float4 xv = *(const float4*)xrow;
        float4 sh = make_float4(0.f, 0.f, 0.f, 0.f);
        if (t > 0) sh = *(const float4*)(xrow - H_);
        float o0 = xv.x + (sh.x - xv.x) * (acc[i][0] + bb[0]);
        float o1 = xv.y + (sh.y - xv.y) * (acc[i][1] + bb[1]);
        float o2 = xv.z + (sh.z - xv.z) * (acc[i][2] + bb[2]);
        float o3 = xv.w + (sh.w - xv.w) * (acc[i][3] + bb[3]);
        if (tiled) {
            int rb = r >> 7, kb = kcol >> 5, g = (kcol >> 3) & 3, hf = (kcol >> 2) & 1;
            ushort4 pk; pk.x = bf16r(o0); pk.y = bf16r(o1); pk.z = bf16r(o2); pk.w = bf16r(o3);
            *(ushort4*)&xmt[(((size_t)(rb * 64 + kb)) << 12) + ((g << 7) + (r & 127)) * 8 + hf * 4] = pk;
        } else {
            float4 o; o.x = o0; o.y = o1; o.z = o2; o.w = o3;
            *(float4*)&xm[(size_t)r * H_ + kcol] = o;
        }
    }
}

// ---------------------------------------------------------------------------
// fp32 GEMM (LoRA up paths). EPI: 1 = tanh, 2 = +bias, 3 = -exp(v+bias)
template<int EPI>
__global__ __launch_bounds__(256) void gemm_f32(const float* __restrict__ A,
                                                const float* __restrict__ W,
                                                const float* __restrict__ bias,
                                                float* __restrict__ C,
                                                int K, int lda, int ldb, int ldc) {
    __shared__ float As[16][68];
    __shared__ float Bs[16][68];
    int tid = threadIdx.x;
    int tx = tid & 15, ty = tid >> 4;
    int row0 = blockIdx.y * 64, col0 = blockIdx.x * 64;
    int am = tid >> 2, ak = (tid & 3) << 2;
    int bk = tid >> 4, bn = (tid & 15) << 2;
    float acc[4][4] = {};
    float4 av = *(const float4*)&A[(size_t)(row0 + am) * lda + ak];
    float4 bv = *(const float4*)&W[(size_t)bk * ldb + col0 + bn];
    for (int k0 = 0; k0 < K; k0 += 16) {
        __syncthreads();
        As[ak + 0][am] = av.x; As[ak + 1][am] = av.y;
        As[ak + 2][am] = av.z; As[ak + 3][am] = av.w;
        *(float4*)&Bs[bk][bn] = bv;
        __syncthreads();
        if (k0 + 16 < K) {
            av = *(const float4*)&A[(size_t)(row0 + am) * lda + k0 + 16 + ak];
            bv = *(const float4*)&W[(size_t)(k0 + 16 + bk) * ldb + col0 + bn];
        }
        #pragma unroll
        for (int kk = 0; kk < 16; ++kk) {
            float4 a = *(const float4*)&As[kk][ty << 2];
            float4 b = *(const float4*)&Bs[kk][tx << 2];
            float aa[4] = {a.x, a.y, a.z, a.w};
            float bb[4] = {b.x, b.y, b.z, b.w};
            #pragma unroll
            for (int i = 0; i < 4; ++i)
                #pragma unroll
                for (int j = 0; j < 4; ++j)
                    acc[i][j] = fmaf(aa[i], bb[j], acc[i][j]);
        }
    }
    #pragma unroll
    for (int i = 0; i < 4; ++i) {
        int r = row0 + (ty << 2) + i;
        #pragma unroll
        for (int j = 0; j < 4; ++j) {
            int c = col0 + (tx << 2) + j;
            float v = acc[i][j];
            if (EPI == 2 || EPI == 3) v += bias[c];
            if (EPI == 1) v = tanhf(v);
            if (EPI == 3) v = -expf(v);   // store LOG decay
            C[(size_t)r * ldc + c] = v;
        }
    }
}

// ---------------------------------------------------------------------------
// Split-K fp32 GEMM for LoRA down-proj: A[2048][2048] @ W[2048][64].
// Grid (8 k-chunks, 32 row-tiles); each block does 64x64 x K=256 partial.
// part[kc][2048][64].
__global__ __launch_bounds__(256) void gemm_f32_splitk(const float* __restrict__ A,
                                                       const float* __restrict__ W,
                                                       float* __restrict__ part) {
    __shared__ float As[16][68];
    __shared__ float Bs[16][68];
    int tid = threadIdx.x;
    int tx = tid & 15, ty = tid >> 4;
    int row0 = blockIdx.y * 64;
    int kbase = blockIdx.x * 256;
    int am = tid >> 2, ak = (tid & 3) << 2;
    int bk = tid >> 4, bn = (tid & 15) << 2;
    float acc[4][4] = {};
    float4 av = *(const float4*)&A[(size_t)(row0 + am) * H_ + kbase + ak];
    float4 bv = *(const float4*)&W[(size_t)(kbase + bk) * 64 + bn];
    for (int k0 = 0; k0 < 256; k0 += 16) {
        __syncthreads();
        As[ak + 0][am] = av.x; As[ak + 1][am] = av.y;
        As[ak + 2][am] = av.z; As[ak + 3][am] = av.w;
        *(float4*)&Bs[bk][bn] = bv;
        __syncthreads();
        if (k0 + 16 < 256) {
            av = *(const float4*)&A[(size_t)(row0 + am) * H_ + kbase + k0 + 16 + ak];
            bv = *(const float4*)&W[(size_t)(kbase + k0 + 16 + bk) * 64 + bn];
        }
        #pragma unroll
        for (int kk = 0; kk < 16; ++kk) {
            float4 a = *(const float4*)&As[kk][ty << 2];
            float4 b = *(const float4*)&Bs[kk][tx << 2];
            float aa[4] = {a.x, a.y, a.z, a.w};
            float bb[4] = {b.x, b.y, b.z, b.w};
            #pragma unroll
            for (int i = 0; i < 4; ++i)
                #pragma unroll
                for (int j = 0; j < 4; ++j)
                    acc[i][j] = fmaf(aa[i], bb[j], acc[i][j]);
        }
    }
    float* pc = part + (size_t)blockIdx.x * (M_ * 64);
    #pragma unroll
    for (int i = 0; i < 4; ++i) {
        int r = row0 + (ty << 2) + i;
        #pragma unroll
        for (int j = 0; j < 4; ++j)
            pc[(size_t)r * 64 + (tx << 2) + j] = acc[i][j];
    }
}

// hid = tanh(sum_kc part[kc])   (2048x64, float4 per thread)
__global__ __launch_bounds__(256) void reduce_tanh(const float* __restrict__ part,
                                                   float* __restrict__ hid) {
    int i = blockIdx.x * 256 + threadIdx.x;       // 32768 float4s
    const float4* p = (const float4*)part;
    float4 s = p[i];
    #pragma unroll
    for (int kc = 1; kc < 8; ++kc) {
        float4 v = p[i + kc * 32768];
        s.x += v.x; s.y += v.y; s.z += v.z; s.w += v.w;
    }
    s.x = tanhf(s.x); s.y = tanhf(s.y); s.z = tanhf(s.z); s.w = tanhf(s.w);
    ((float4*)hid)[i] = s;
}

// ---------------------------------------------------------------------------
// Chunked scan, phase A.
__global__ __launch_bounds__(256) void scan_chunkA(const float* r, const float* k,
                                                   const float* v, const float* ld,
                                                   const float* u,
                                                   float* rt, float* ointra,
                                                   float* Bc, float* Dc) {
    __shared__ float sR[CC_][68], sK[CC_][68], sV[CC_][68], sW[CC_][68];
    __shared__ float wc[CC_ + 1][64];
    __shared__ float sA[CC_][36];
    __shared__ float diag[CC_];
    __shared__ float sU[64];
    int bid = blockIdx.x;
    int bh = bid >> 5, c = bid & (NC_ - 1);
    int b = bh >> 4, h = bh & 15;
    int tid = threadIdx.x;
    size_t base = ((size_t)(b * T_ + c * CC_)) * KD_ + h * 64;

    for (int q = tid; q < CC_ * 16; q += 256) {
        int row = q >> 4, col4 = (q & 15) << 2;
        size_t gi = base + (size_t)row * KD_ + col4;
        *(float4*)&sR[row][col4] = *(const float4*)&r[gi];
        *(float4*)&sK[row][col4] = *(const float4*)&k[gi];
        *(float4*)&sV[row][col4] = *(const float4*)&v[gi];
        *(float4*)&sW[row][col4] = *(const float4*)&ld[gi];
    }
    if (tid < 64) sU[tid] = u[h * 64 + tid];
    __syncthreads();

    if (tid < 64) {
        float acc = 0.f;
        wc[0][tid] = 0.f;
        #pragma unroll
        for (int s = 0; s < CC_; ++s) { acc += sW[s][tid]; wc[s + 1][tid] = acc; }
    }
    {
        int tau = tid >> 3, g = tid & 7;
        float p = 0.f;
        #pragma unroll
        for (int q = 0; q < 8; ++q) {
            int i = g * 8 + q;
            p += sR[tau][i] * sU[i] * sK[tau][i];
        }
        p += __shfl_xor(p, 1, 64); p += __shfl_xor(p, 2, 64); p += __shfl_xor(p, 4, 64);
        if (g == 0) diag[tau] = p;
    }
    __syncthreads();

    for (int q = tid; q < CC_ * 64; q += 256) {
        int s = q >> 6, i = q & 63;
        float wcs  = wc[s][i];
        float wcs1 = wc[s + 1][i];
        float wcc  = wc[CC_][i];
        float rt_ = sR[s][i] * expf(wcs);
        float kt_ = sK[s][i] * expf(-wcs1);
        float bb  = sK[s][i] * expf(wcc - wcs1);
        sR[s][i] = rt_;
        sW[s][i] = kt_;
        sK[s][i] = bb;
        rt[base + (size_t)s * KD_ + i] = rt_;
    }
    if (tid < 64) Dc[(size_t)bid * 64 + tid] = expf(wc[CC_][tid]);
    __syncthreads();

    {
        int tau = tid >> 3, s0 = (tid & 7) * 4;
        float a0 = 0, a1 = 0, a2 = 0, a3 = 0;
        for (int i = 0; i < 64; i += 4) {
            float4 rr = *(const float4*)&sR[tau][i];
            float4 k0v = *(const float4*)&sW[s0 + 0][i];
            float4 k1v = *(const float4*)&sW[s0 + 1][i];
            float4 k2v = *(const float4*)&sW[s0 + 2][i];
            float4 k3v = *(const float4*)&sW[s0 + 3][i];
            a0 += rr.x * k0v.x + rr.y * k0v.y + rr.z * k0v.z + rr.w * k0v.w;
            a1 += rr.x * k1v.x + rr.y * k1v.y + rr.z * k1v.z + rr.w * k1v.w;
            a2 += rr.x * k2v.x + rr.y * k2v.y + rr.z * k2v.z + rr.w * k2v.w;
            a3 += rr.x * k3v.x + rr.y * k3v.y + rr.z * k3v.z + rr.w * k3v.w;
        }
        sA[tau][s0 + 0] = (s0 + 0 < tau) ? a0 : ((s0 + 0 == tau) ? diag[tau] : 0.f);
        sA[tau][s0 + 1] = (s0 + 1 < tau) ? a1 : ((s0 + 1 == tau) ? diag[tau] : 0.f);
        sA[tau][s0 + 2] = (s0 + 2 < tau) ? a2 : ((s0 + 2 == tau) ? diag[tau] : 0.f);
        sA[tau][s0 + 3] = (s0 + 3 < tau) ? a3 : ((s0 + 3 == tau) ? diag[tau] : 0.f);
    }
    __syncthreads();

    {
        int tau = tid >> 3, j0 = (tid & 7) * 8;
        float o_[8] __attribute__((aligned(16))) = {};
        for (int s = 0; s < CC_; ++s) {
            float a = sA[tau][s];
            #pragma unroll
            for (int q = 0; q < 8; ++q) o_[q] += a * sV[s][j0 + q];
        }
        size_t ob = base + (size_t)tau * KD_ + j0;
        *(float4*)&ointra[ob]     = *(float4*)&o_[0];
        *(float4*)&ointra[ob + 4] = *(float4*)&o_[4];
    }
    {
        int i = tid >> 2, j0 = (tid & 3) * 16;
        float bacc[16] __attribute__((aligned(16))) = {};
        for (int s = 0; s < CC_; ++s) {
            float bi = sK[s][i];
            #pragma unroll
            for (int q = 0; q < 16; ++q) bacc[q] += bi * sV[s][j0 + q];
        }
        size_t bb = ((size_t)bid << 12) + i * 64 + j0;
        *(float4*)&Bc[bb + 0]  = *(float4*)&bacc[0];
        *(float4*)&Bc[bb + 4]  = *(float4*)&bacc[4];
        *(float4*)&Bc[bb + 8]  = *(float4*)&bacc[8];
        *(float4*)&Bc[bb + 12] = *(float4*)&bacc[12];
    }
}

// ---------------------------------------------------------------------------
__global__ __launch_bounds__(256) void scan_chunkB(float* BS, const float* __restrict__ Dc) {
    int g = blockIdx.x * 256 + threadIdx.x;
    int bh = g >> 12, ij = g & 4095, i = ij >> 6;
    float S = 0.f;
    size_t base = ((size_t)bh << 17) + ij;
    for (int c = 0; c < NC_; ++c) {
        size_t idx = base + ((size_t)c << 12);
        float bv = BS[idx];
        float d = Dc[(size_t)(bh * NC_ + c) * 64 + i];
        BS[idx] = S;
        S = d * S + bv;
    }
}

// ---------------------------------------------------------------------------
__global__ __launch_bounds__(256) void scan_chunkC(const float* __restrict__ rt,
                                                   const float* __restrict__ BS,
                                                   float* o) {
    __shared__ float sS[64][64];
    __shared__ float sRt[CC_][68];
    int bid = blockIdx.x;
    int bh = bid >> 5, c = bid & (NC_ - 1);
    int b = bh >> 4, h = bh & 15;
    int tid = threadIdx.x;
    size_t sbase = ((size_t)bid) << 12;
    for (int q = tid; q < 1024; q += 256)
        *(float4*)&sS[q >> 4][(q & 15) << 2] = *(const float4*)&BS[sbase + (q << 2)];
    size_t base = ((size_t)(b * T_ + c * CC_)) * KD_ + h * 64;
    for (int q = tid; q < CC_ * 16; q += 256) {
        int row = q >> 4, col4 = (q & 15) << 2;
        *(float4*)&sRt[row][col4] = *(const float4*)&rt[base + (size_t)row * KD_ + col4];
    }
    __syncthreads();
    int tau = tid >> 3, j0 = (tid & 7) * 8;
    size_t obase = base + (size_t)tau * KD_ + j0;
    float acc[8] __attribute__((aligned(16)));
    *(float4*)&acc[0] = *(const float4*)&o[obase];
    *(float4*)&acc[4] = *(const float4*)&o[obase + 4];
    for (int i = 0; i < 64; ++i) {
        float a = sRt[tau][i];
        #pragma unroll
        for (int q = 0; q < 8; ++q) acc[q] += a * sS[i][j0 + q];
    }
    *(float4*)&o[obase]     = *(float4*)&acc[0];
    *(float4*)&o[obase + 4] = *(float4*)&acc[4];
}

// ---------------------------------------------------------------------------
// Per-head LN + swish gate -> tiled bf16 A-layout (K=1024, KB=32)
__global__ __launch_bounds__(256) void lngate_kernel(const float* __restrict__ o,
                                                     const float* __restrict__ g,
                                                     const float* __restrict__ lw,
                                                     const float* __restrict__ lb,
                                                     ushort* __restrict__ outt) {
    int rr = blockIdx.x * 4 + (threadIdx.x >> 6);   // (bt*16 + h)
    int c = threadIdx.x & 63;
    size_t idx = (size_t)rr * 64 + c;
    float oc = o[idx];
    float s = oc;
    #pragma unroll
    for (int m = 32; m >= 1; m >>= 1) s += __shfl_xor(s, m, 64);
    float mean = s * (1.f / 64.f);
    float dx = oc - mean;
    float s2 = dx * dx;
    #pragma unroll
    for (int m = 32; m >= 1; m >>= 1) s2 += __shfl_xor(s2, m, 64);
    float var = s2 * (1.f / 64.f);
    float on = dx * rsqrtf(var + 1e-5f) * lw[c] + lb[c];
    float gv = g[idx];
    float val = on * gv / (1.f + expf(-gv));
    int mrow = rr >> 4;
    int col = ((rr & 15) << 6) + c;
    int rb = mrow >> 7, kb = col >> 5, gg = (col >> 3) & 3;
    outt[(((size_t)(rb * 32 + kb)) << 12) + ((gg << 7) + (mrow & 127)) * 8 + (col & 7)] = bf16r(val);
}

// ---------------------------------------------------------------------------
extern "C" void kernel_launch(void* const* d_in, const int* in_sizes, int n_in,
                              void* d_out, int out_size, void* d_ws, size_t ws_size,
                              hipStream_t stream) {
    const float* x     = (const float*)d_in[0];
    const float* mu_x  = (const float*)d_in[1];
    const float* Wx1   = (const float*)d_in[2];
    const float* Wx2   = (const float*)d_in[3];
    const float* xbias = (const float*)d_in[4];
    const float* Wr    = (const float*)d_in[5];
    const float* Wk    = (const float*)d_in[6];
    const float* Wv    = (const float*)d_in[7];
    const float* Ww_a  = (const float*)d_in[8];
    const float* Ww_b  = (const float*)d_in[9];
    const float* bw    = (const float*)d_in[10];
    const float* Wg_a  = (const float*)d_in[11];
    const float* Wg_b  = (const float*)d_in[12];
    const float* bg    = (const float*)d_in[13];
    const float* bonus = (const float*)d_in[14];
    const float* ln_w  = (const float*)d_in[15];
    const float* ln_b  = (const float*)d_in[16];
    const float* Wo    = (const float*)d_in[17];
    float* out = (float*)d_out;

    // workspace layout (float units)
    float* ws  = (float*)d_ws;
    float* xm  = ws;                                // M_*H_ fp32 (branches w,g)
    float* lr  = xm  + (size_t)M_ * H_;             // M_*320
    float* hid = lr  + (size_t)M_ * 320;            // M_*64
    float* rb_ = hid + (size_t)M_ * 64;             // M_*KD_
    float* kb_ = rb_ + (size_t)M_ * KD_;
    float* vb_ = kb_ + (size_t)M_ * KD_;
    float* db_ = vb_ + (size_t)M_ * KD_;            // log-decay
    float* gb_ = db_ + (size_t)M_ * KD_;            // raw gate
    float* ob_ = gb_ + (size_t)M_ * KD_;            // o_intra then final o
    float* BS  = ob_ + (size_t)M_ * KD_;            // 1024*4096 (scan); also split-K partials
    float* Dc  = BS  + (size_t)1024 * 4096;         // 1024*64
    float* wend = Dc + (size_t)1024 * 64;
    // bf16 regions (ushort units)
    ushort* xmt  = (ushort*)xm;                     // overlay: tiled bf16 xm (8 MB)
    ushort* gt   = (ushort*)(xm + (size_t)M_ * H_ / 2);  // tiled gated (4 MB), after xmt
    ushort* Wx1t = (ushort*)wend;                   // 2048*320
    ushort* Wrt  = Wx1t + (size_t)H_ * 320;
    ushort* Wkt  = Wrt  + (size_t)H_ * KD_;
    ushort* Wvt  = Wkt  + (size_t)H_ * KD_;
    ushort* Wot  = Wvt  + (size_t)H_ * KD_;         // 1024*2048

    dim3 blk(256);
    const int elems8 = M_ * H_ / 8;

    // 0. weight conversions (tiled bf16)
    convert_w<<<dim3(320 / 64, H_ / 32), blk, 0, stream>>>(Wx1, Wx1t, H_, 320);
    convert_w<<<dim3(KD_ / 64, H_ / 32), blk, 0, stream>>>(Wr, Wrt, H_, KD_);
    convert_w<<<dim3(KD_ / 64, H_ / 32), blk, 0, stream>>>(Wk, Wkt, H_, KD_);
    convert_w<<<dim3(KD_ / 64, H_ / 32), blk, 0, stream>>>(Wv, Wvt, H_, KD_);
    convert_w<<<dim3(H_ / 64, KD_ / 32), blk, 0, stream>>>(Wo, Wot, KD_, H_);

    // 1. lr = tanh((x + delta*mu_x) @ Wx1)   [bf16 MFMA]
    mix_mu_t<<<elems8 / 256, blk, 0, stream>>>(x, mu_x, xmt);
    gemm_bf16t<1><<<dim3(320 / 64, M_ / 128), blk, 0, stream>>>(xmt, Wx1t, lr, H_, 320);

    // 2. branch r  [bf16 MFMA]
    musgemm_kernel<<<dim3(H_ / 64, M_ / 64), blk, 0, stream>>>(x, lr, Wx2, xbias, nullptr, xmt, 0, 1);
    gemm_bf16t<0><<<dim3(KD_ / 64, M_ / 128), blk, 0, stream>>>(xmt, Wrt, rb_, H_, KD_);

    // 3. branch w (decay path stays fp32; split-K down-proj, partials in BS)
    musgemm_kernel<<<dim3(H_ / 64, M_ / 64), blk, 0, stream>>>(x, lr, Wx2, xbias, xm, nullptr, 1, 0);
    gemm_f32_splitk<<<dim3(8, M_ / 64), blk, 0, stream>>>(xm, Ww_a, BS);
    reduce_tanh<<<128, blk, 0, stream>>>(BS, hid);
    gemm_f32<3><<<dim3(KD_ / 64, M_ / 64), blk, 0, stream>>>(hid, Ww_b, bw, db_, 64, 64, KD_, KD_);

    // 4. branch k  [bf16 MFMA]
    musgemm_kernel<<<dim3(H_ / 64, M_ / 64), blk, 0, stream>>>(x, lr, Wx2, xbias, nullptr, xmt, 2, 1);
    gemm_bf16t<0><<<dim3(KD_ / 64, M_ / 128), blk, 0, stream>>>(xmt, Wkt, kb_, H_, KD_);

    // 5. branch v  [bf16 MFMA]
    musgemm_kernel<<<dim3(H_ / 64, M_ / 64), blk, 0, stream>>>(x, lr, Wx2, xbias, nullptr, xmt, 3, 1);
    gemm_bf16t<0><<<dim3(KD_ / 64, M_ / 128), blk, 0, stream>>>(xmt, Wvt, vb_, H_, KD_);

    // 6. branch g (gate path stays fp32; split-K down-proj)
    musgemm_kernel<<<dim3(H_ / 64, M_ / 64), blk, 0, stream>>>(x, lr, Wx2, xbias, xm, nullptr, 4, 0);
    gemm_f32_splitk<<<dim3(8, M_ / 64), blk, 0, stream>>>(xm, Wg_a, BS);
    reduce_tanh<<<128, blk, 0, stream>>>(BS, hid);
    gemm_f32<2><<<dim3(KD_ / 64, M_ / 64), blk, 0, stream>>>(hid, Wg_b, bg, gb_, 64, 64, KD_, KD_);

    // 7. chunk-parallel scan (fp32)
    scan_chunkA<<<B_ * NH_ * NC_, blk, 0, stream>>>(rb_, kb_, vb_, db_, bonus,
                                                    rb_ /*rt in place*/, ob_, BS, Dc);
    scan_chunkB<<<(B_ * NH_ * 4096) / 256, blk, 0, stream>>>(BS, Dc);
    scan_chunkC<<<B_ * NH_ * NC_, blk, 0, stream>>>(rb_, BS, ob_);

    // 8. LN + swish gate -> tiled bf16
    lngate_kernel<<<(M_ * NH_) / 4, blk, 0, stream>>>(ob_, gb_, ln_w, ln_b, gt);

    // 9. out = gated @ Wo  [bf16 MFMA]
    gemm_bf16t<0><<<dim3(H_ / 64, M_ / 128), blk, 0, stream>>>(gt, Wot, out, KD_, H_);
}

// Round 6
// 357.138 us; speedup vs baseline: 7.2959x; 1.0306x over previous
//
#include <hip/hip_runtime.h>
#include <hip/hip_bf16.h>

#define H_    2048
#define NH_   16
#define KD_   1024
#define DK_   64
#define T_    1024
#define B_    2
#define M_    (B_*T_)     // 2048 rows
#define RL_   64
#define CC_   32          // scan chunk length
#define NC_   (T_/CC_)    // 32 chunks per sequence

typedef short bf16x8 __attribute__((ext_vector_type(8)));   // 8 bf16 (4 VGPR)
typedef float f32x4  __attribute__((ext_vector_type(4)));   // MFMA acc

__device__ __forceinline__ ushort bf16r(float f) {          // RNE fp32->bf16
    union { float f; unsigned u; } v; v.f = f;
    return (ushort)((v.u + 0x7FFF + ((v.u >> 16) & 1)) >> 16);
}

// ---------------------------------------------------------------------------
// Tiled bf16 layouts:
//  A-tiles (BM=128, BK=32): tile id (rb*KB + kb), 4096 bf16/tile,
//    elem (r,k): off = (g*128 + r)*8 + (k&7),  g=(k>>3)&3
//  B-tiles (BN=64, BK=32): tile id (nb*KB + kb), 2048 bf16/tile,
//    elem (c,k): off = (g*64 + c)*8 + (k&7)
// ---------------------------------------------------------------------------

// xx = x + (shift(x)-x)*mu_x  -> tiled bf16 A-layout (chunk per thread)
__global__ __launch_bounds__(256) void mix_mu_t(const float* __restrict__ x,
                                                const float* __restrict__ mu,
                                                ushort* __restrict__ At) {
    int c = blockIdx.x * 256 + threadIdx.x;       // chunk id 0..M_*H_/8
    int bt = c >> 8, k8 = c & 255;
    int k = k8 << 3;
    int t = bt & (T_ - 1);
    const float* xp = &x[(size_t)bt * H_ + k];
    float4 xa = *(const float4*)xp;
    float4 xb = *(const float4*)(xp + 4);
    float4 sa = make_float4(0,0,0,0), sb = make_float4(0,0,0,0);
    if (t > 0) { sa = *(const float4*)(xp - H_); sb = *(const float4*)(xp - H_ + 4); }
    float4 ma = *(const float4*)&mu[k];
    float4 mb = *(const float4*)&mu[k + 4];
    ushort o[8];
    o[0] = bf16r(xa.x + (sa.x - xa.x) * ma.x);
    o[1] = bf16r(xa.y + (sa.y - xa.y) * ma.y);
    o[2] = bf16r(xa.z + (sa.z - xa.z) * ma.z);
    o[3] = bf16r(xa.w + (sa.w - xa.w) * ma.w);
    o[4] = bf16r(xb.x + (sb.x - xb.x) * mb.x);
    o[5] = bf16r(xb.y + (sb.y - xb.y) * mb.y);
    o[6] = bf16r(xb.z + (sb.z - xb.z) * mb.z);
    o[7] = bf16r(xb.w + (sb.w - xb.w) * mb.w);
    int rb = bt >> 7, kb = k8 >> 2, g = k8 & 3, r = bt & 127;
    *(uint4*)&At[(((size_t)(rb * 64 + kb)) << 12) + ((g << 7) + r) * 8] = *(uint4*)o;
}

// ---------------------------------------------------------------------------
// W [K][N] fp32 -> tiled bf16 B-layout (per 32x64 tile block, LDS transpose)
__global__ __launch_bounds__(256) void convert_w(const float* __restrict__ W,
                                                 ushort* __restrict__ Wt,
                                                 int K, int N) {
    __shared__ float s[32][68];
    int kb = blockIdx.y, nb = blockIdx.x;
    int t = threadIdx.x;
    #pragma unroll
    for (int i = 0; i < 2; ++i) {
        int q = t + i * 256;                       // 0..511 float4s
        int k = q >> 4, c4 = (q & 15) << 2;
        *(float4*)&s[k][c4] = *(const float4*)&W[(size_t)(kb * 32 + k) * N + nb * 64 + c4];
    }
    __syncthreads();
    int g = t >> 6, c = t & 63;
    ushort o[8];
    #pragma unroll
    for (int e = 0; e < 8; ++e) o[e] = bf16r(s[g * 8 + e][c]);
    *(uint4*)&Wt[((size_t)(nb * (K >> 5) + kb)) * 2048 + t * 8] = *(uint4*)o;
}

// ---------------------------------------------------------------------------
// bf16 MFMA GEMM: C[M][ldc] = epi(A @ B), A tiled bf16 (BM=128), B tiled (BN=64).
// 256 thr = 4 waves (2x2), wave = 64x32 out = 4x2 frags of 16x16, BK=32.
// EPI: 0 = none, 1 = tanh
template<int EPI>
__global__ __launch_bounds__(256) void gemm_bf16t(const ushort* __restrict__ At,
                                                  const ushort* __restrict__ Bt,
                                                  float* __restrict__ C,
                                                  int K, int ldc) {
    __shared__ ushort Alds[4096];
    __shared__ ushort Blds[2048];
    int tid = threadIdx.x;
    int w = tid >> 6, l = tid & 63;
    int KB = K >> 5;
    const ushort* Ag = At + (size_t)blockIdx.y * KB * 4096 + tid * 8;
    const ushort* Bg = Bt + (size_t)blockIdx.x * KB * 2048 + tid * 8;
    int wr = (w >> 1) << 6, wc = (w & 1) << 5;
    int a_off = (((l >> 4) << 7) + wr + (l & 15)) << 3;   // (g*128 + row)*8
    int b_off = (((l >> 4) << 6) + wc + (l & 15)) << 3;   // (g*64 + col)*8
    f32x4 acc[8] = {};
    uint4 a0 = *(const uint4*)(Ag);
    uint4 a1 = *(const uint4*)(Ag + 2048);
    uint4 b0 = *(const uint4*)(Bg);
    for (int kt = 0; kt < KB; ++kt) {
        __syncthreads();                       // prior ds_reads done
        *(uint4*)&Alds[tid * 8] = a0;
        *(uint4*)&Alds[tid * 8 + 2048] = a1;
        *(uint4*)&Blds[tid * 8] = b0;
        __syncthreads();
        if (kt + 1 < KB) {                     // prefetch next K-tile
            Ag += 4096; Bg += 2048;
            a0 = *(const uint4*)(Ag);
            a1 = *(const uint4*)(Ag + 2048);
            b0 = *(const uint4*)(Bg);
        }
        bf16x8 af0 = *(const bf16x8*)&Alds[a_off];
        bf16x8 af1 = *(const bf16x8*)&Alds[a_off + 128];
        bf16x8 af2 = *(const bf16x8*)&Alds[a_off + 256];
        bf16x8 af3 = *(const bf16x8*)&Alds[a_off + 384];
        bf16x8 bf0 = *(const bf16x8*)&Blds[b_off];
        bf16x8 bf1 = *(const bf16x8*)&Blds[b_off + 128];
        acc[0] = __builtin_amdgcn_mfma_f32_16x16x32_bf16(af0, bf0, acc[0], 0, 0, 0);
        acc[1] = __builtin_amdgcn_mfma_f32_16x16x32_bf16(af0, bf1, acc[1], 0, 0, 0);
        acc[2] = __builtin_amdgcn_mfma_f32_16x16x32_bf16(af1, bf0, acc[2], 0, 0, 0);
        acc[3] = __builtin_amdgcn_mfma_f32_16x16x32_bf16(af1, bf1, acc[3], 0, 0, 0);
        acc[4] = __builtin_amdgcn_mfma_f32_16x16x32_bf16(af2, bf0, acc[4], 0, 0, 0);
        acc[5] = __builtin_amdgcn_mfma_f32_16x16x32_bf16(af2, bf1, acc[5], 0, 0, 0);
        acc[6] = __builtin_amdgcn_mfma_f32_16x16x32_bf16(af3, bf0, acc[6], 0, 0, 0);
        acc[7] = __builtin_amdgcn_mfma_f32_16x16x32_bf16(af3, bf1, acc[7], 0, 0, 0);
    }
    int row0 = (blockIdx.y << 7) + wr + ((l >> 4) << 2);
    int col0 = (blockIdx.x << 6) + wc + (l & 15);
    #pragma unroll
    for (int fr = 0; fr < 4; ++fr)
        #pragma unroll
        for (int fc = 0; fc < 2; ++fc) {
            f32x4 v = acc[fr * 2 + fc];
            #pragma unroll
            for (int q = 0; q < 4; ++q) {
                float o = v[q];
                if (EPI == 1) o = tanhf(o);
                C[(size_t)(row0 + fr * 16 + q) * ldc + col0 + fc * 16] = o;
            }
        }
}

// ---------------------------------------------------------------------------
// Fused 5-branch mus-GEMM + lerp. One 64x64 (bt,h) tile per block; x staged
// once; per branch: stage lr/Wx2 slice, K=64 fp32 GEMM, lerp epilogue to the
// branch-specific destination (r/k/v tiled bf16; w/g fp32 row-major).
__global__ __launch_bounds__(256) void musgemm5_kernel(const float* __restrict__ x,
                                                       const float* __restrict__ lr,
                                                       const float* __restrict__ Wx2,
                                                       const float* __restrict__ xbias,
                                                       ushort* __restrict__ xmt_r,
                                                       float*  __restrict__ xm_w,
                                                       ushort* __restrict__ xmt_k,
                                                       ushort* __restrict__ xmt_v,
                                                       float*  __restrict__ xm_g) {
    __shared__ float sX[65][68];   // rows row0-1 .. row0+63
    __shared__ float sL[64][68];
    __shared__ float sW[64][68];
    int tid = threadIdx.x;
    int tx = tid & 15, ty = tid >> 4;
    int col0 = blockIdx.x * 64;    // h
    int row0 = blockIdx.y * 64;    // bt
    for (int q = tid; q < 65 * 16; q += 256) {
        int rr = q >> 4, c4 = (q & 15) << 2;
        int gr = row0 + rr - 1;
        float4 v = make_float4(0.f, 0.f, 0.f, 0.f);
        if (gr >= 0) v = *(const float4*)&x[(size_t)gr * H_ + col0 + c4];
        *(float4*)&sX[rr][c4] = v;
    }
    int kcol = col0 + (tx << 2);
    #pragma unroll
    for (int b = 0; b < 5; ++b) {
        __syncthreads();   // prior-branch acc reads done (and sX staged, b==0)
        for (int q = tid; q < 1024; q += 256) {
            int r = q >> 4, k4 = (q & 15) << 2;
            *(float4*)&sL[r][k4] = *(const float4*)&lr[(size_t)(row0 + r) * 320 + b * 64 + k4];
            *(float4*)&sW[r][k4] = *(const float4*)&Wx2[(size_t)(col0 + r) * 320 + b * 64 + k4];
        }
        __syncthreads();
        float acc[4][4] = {};
        for (int k = 0; k < 64; k += 4) {
            float4 a[4], bb[4];
            #pragma unroll
            for (int i = 0; i < 4; ++i) a[i] = *(const float4*)&sL[(ty << 2) + i][k];
            #pragma unroll
            for (int j = 0; j < 4; ++j) bb[j] = *(const float4*)&sW[(tx << 2) + j][k];
            #pragma unroll
            for (int i = 0; i < 4; ++i)
                #pragma unroll
                for (int j = 0; j < 4; ++j)
                    acc[i][j] += a[i].x * bb[j].x + a[i].y * bb[j].y
                               + a[i].z * bb[j].z + a[i].w * bb[j].w;
        }
        float4 bias4 = *(const float4*)&xbias[b * H_ + kcol];
        float bv[4] = {bias4.x, bias4.y, bias4.z, bias4.w};
        #pragma unroll
        for (int i = 0; i < 4; ++i) {
            int sr = (ty << 2) + i + 1;
            int r = row0 + (ty << 2) + i;
            int t = r & (T_ - 1);
            float4 xv = *(const float4*)&sX[sr][tx << 2];
            float4 sh = make_float4(0.f, 0.f, 0.f, 0.f);
            if (t > 0) sh = *(const float4*)&sX[sr - 1][tx << 2];
            float o0 = xv.x + (sh.x - xv.x) * (acc[i][0] + bv[0]);
            float o1 = xv.y + (sh.y - xv.y) * (acc[i][1] + bv[1]);
            float o2 = xv.z + (sh.z - xv.z) * (acc[i][2] + bv[2]);
            float o3 = xv.w + (sh.w - xv.w) * (acc[i][3] + bv[3]);
            if (b == 0 || b == 2 || b == 3) {
                ushort* dst = (b == 0) ? xmt_r : (b == 2) ? xmt_k : xmt_v;
                int rb = r >> 7, kb = kcol >> 5, g = (kcol >> 3) & 3, hf = (kcol >> 2) & 1;
                ushort4 pk; pk.x = bf16r(o0); pk.y = bf16r(o1); pk.z = bf16r(o2); pk.w = bf16r(o3);
                *(ushort4*)&dst[(((size_t)(rb * 64 + kb)) << 12) + ((g << 7) + (r & 127)) * 8 + hf * 4] = pk;
            } else {
                float* dst = (b == 1) ? xm_w : xm_g;
                float4 o; o.x = o0; o.y = o1; o.z = o2; o.w = o3;
                *(float4*)&dst[(size_t)r * H_ + kcol] = o;
            }
        }
    }
}

// ---------------------------------------------------------------------------
// fp32 GEMM (LoRA up paths). EPI: 1 = tanh, 2 = +bias, 3 = -exp(v+bias)
template<int EPI>
__global__ __launch_bounds__(256) void gemm_f32(const float* __restrict__ A,
                                                const float* __restrict__ W,
                                                const float* __restrict__ bias,
                                                float* __restrict__ C,
                                                int K, int lda, int ldb, int ldc) {
    __shared__ float As[16][68];
    __shared__ float Bs[16][68];
    int tid = threadIdx.x;
    int tx = tid & 15, ty = tid >> 4;
    int row0 = blockIdx.y * 64, col0 = blockIdx.x * 64;
    int am = tid >> 2, ak = (tid & 3) << 2;
    int bk = tid >> 4, bn = (tid & 15) << 2;
    float acc[4][4] = {};
    float4 av = *(const float4*)&A[(size_t)(row0 + am) * lda + ak];
    float4 bv = *(const float4*)&W[(size_t)bk * ldb + col0 + bn];
    for (int k0 = 0; k0 < K; k0 += 16) {
        __syncthreads();
        As[ak + 0][am] = av.x; As[ak + 1][am] = av.y;
        As[ak + 2][am] = av.z; As[ak + 3][am] = av.w;
        *(float4*)&Bs[bk][bn] = bv;
        __syncthreads();
        if (k0 + 16 < K) {
            av = *(const float4*)&A[(size_t)(row0 + am) * lda + k0 + 16 + ak];
            bv = *(const float4*)&W[(size_t)(k0 + 16 + bk) * ldb + col0 + bn];
        }
        #pragma unroll
        for (int kk = 0; kk < 16; ++kk) {
            float4 a = *(const float4*)&As[kk][ty << 2];
            float4 b = *(const float4*)&Bs[kk][tx << 2];
            float aa[4] = {a.x, a.y, a.z, a.w};
            float bb[4] = {b.x, b.y, b.z, b.w};
            #pragma unroll
            for (int i = 0; i < 4; ++i)
                #pragma unroll
                for (int j = 0; j < 4; ++j)
                    acc[i][j] = fmaf(aa[i], bb[j], acc[i][j]);
        }
    }
    #pragma unroll
    for (int i = 0; i < 4; ++i) {
        int r = row0 + (ty << 2) + i;
        #pragma unroll
        for (int j = 0; j < 4; ++j) {
            int c = col0 + (tx << 2) + j;
            float v = acc[i][j];
            if (EPI == 2 || EPI == 3) v += bias[c];
            if (EPI == 1) v = tanhf(v);
            if (EPI == 3) v = -expf(v);   // store LOG decay
            C[(size_t)r * ldc + c] = v;
        }
    }
}

// ---------------------------------------------------------------------------
// Split-K fp32 GEMM for LoRA down-proj: A[2048][2048] @ W[2048][64].
__global__ __launch_bounds__(256) void gemm_f32_splitk(const float* __restrict__ A,
                                                       const float* __restrict__ W,
                                                       float* __restrict__ part) {
    __shared__ float As[16][68];
    __shared__ float Bs[16][68];
    int tid = threadIdx.x;
    int tx = tid & 15, ty = tid >> 4;
    int row0 = blockIdx.y * 64;
    int kbase = blockIdx.x * 256;
    int am = tid >> 2, ak = (tid & 3) << 2;
    int bk = tid >> 4, bn = (tid & 15) << 2;
    float acc[4][4] = {};
    float4 av = *(const float4*)&A[(size_t)(row0 + am) * H_ + kbase + ak];
    float4 bv = *(const float4*)&W[(size_t)(kbase + bk) * 64 + bn];
    for (int k0 = 0; k0 < 256; k0 += 16) {
        __syncthreads();
        As[ak + 0][am] = av.x; As[ak + 1][am] = av.y;
        As[ak + 2][am] = av.z; As[ak + 3][am] = av.w;
        *(float4*)&Bs[bk][bn] = bv;
        __syncthreads();
        if (k0 + 16 < 256) {
            av = *(const float4*)&A[(size_t)(row0 + am) * H_ + kbase + k0 + 16 + ak];
            bv = *(const float4*)&W[(size_t)(kbase + k0 + 16 + bk) * 64 + bn];
        }
        #pragma unroll
        for (int kk = 0; kk < 16; ++kk) {
            float4 a = *(const float4*)&As[kk][ty << 2];
            float4 b = *(const float4*)&Bs[kk][tx << 2];
            float aa[4] = {a.x, a.y, a.z, a.w};
            float bb[4] = {b.x, b.y, b.z, b.w};
            #pragma unroll
            for (int i = 0; i < 4; ++i)
                #pragma unroll
                for (int j = 0; j < 4; ++j)
                    acc[i][j] = fmaf(aa[i], bb[j], acc[i][j]);
        }
    }
    float* pc = part + (size_t)blockIdx.x * (M_ * 64);
    #pragma unroll
    for (int i = 0; i < 4; ++i) {
        int r = row0 + (ty << 2) + i;
        #pragma unroll
        for (int j = 0; j < 4; ++j)
            pc[(size_t)r * 64 + (tx << 2) + j] = acc[i][j];
    }
}

// hid = tanh(sum_kc part[kc])   (2048x64, float4 per thread)
__global__ __launch_bounds__(256) void reduce_tanh(const float* __restrict__ part,
                                                   float* __restrict__ hid) {
    int i = blockIdx.x * 256 + threadIdx.x;       // 32768 float4s
    const float4* p = (const float4*)part;
    float4 s = p[i];
    #pragma unroll
    for (int kc = 1; kc < 8; ++kc) {
        float4 v = p[i + kc * 32768];
        s.x += v.x; s.y += v.y; s.z += v.z; s.w += v.w;
    }
    s.x = tanhf(s.x); s.y = tanhf(s.y); s.z = tanhf(s.z); s.w = tanhf(s.w);
    ((float4*)hid)[i] = s;
}

// ---------------------------------------------------------------------------
// Chunked scan, phase A.
__global__ __launch_bounds__(256) void scan_chunkA(const float* r, const float* k,
                                                   const float* v, const float* ld,
                                                   const float* u,
                                                   float* rt, float* ointra,
                                                   float* Bc, float* Dc) {
    __shared__ float sR[CC_][68], sK[CC_][68], sV[CC_][68], sW[CC_][68];
    __shared__ float wc[CC_ + 1][64];
    __shared__ float sA[CC_][36];
    __shared__ float diag[CC_];
    __shared__ float sU[64];
    int bid = blockIdx.x;
    int bh = bid >> 5, c = bid & (NC_ - 1);
    int b = bh >> 4, h = bh & 15;
    int tid = threadIdx.x;
    size_t base = ((size_t)(b * T_ + c * CC_)) * KD_ + h * 64;

    for (int q = tid; q < CC_ * 16; q += 256) {
        int row = q >> 4, col4 = (q & 15) << 2;
        size_t gi = base + (size_t)row * KD_ + col4;
        *(float4*)&sR[row][col4] = *(const float4*)&r[gi];
        *(float4*)&sK[row][col4] = *(const float4*)&k[gi];
        *(float4*)&sV[row][col4] = *(const float4*)&v[gi];
        *(float4*)&sW[row][col4] = *(const float4*)&ld[gi];
    }
    if (tid < 64) sU[tid] = u[h * 64 + tid];
    __syncthreads();

    if (tid < 64) {
        float acc = 0.f;
        wc[0][tid] = 0.f;
        #pragma unroll
        for (int s = 0; s < CC_; ++s) { acc += sW[s][tid]; wc[s + 1][tid] = acc; }
    }
    {
        int tau = tid >> 3, g = tid & 7;
        float p = 0.f;
        #pragma unroll
        for (int q = 0; q < 8; ++q) {
            int i = g * 8 + q;
            p += sR[tau][i] * sU[i] * sK[tau][i];
        }
        p += __shfl_xor(p, 1, 64); p += __shfl_xor(p, 2, 64); p += __shfl_xor(p, 4, 64);
        if (g == 0) diag[tau] = p;
    }
    __syncthreads();

    for (int q = tid; q < CC_ * 64; q += 256) {
        int s = q >> 6, i = q & 63;
        float wcs  = wc[s][i];
        float wcs1 = wc[s + 1][i];
        float wcc  = wc[CC_][i];
        float rt_ = sR[s][i] * expf(wcs);
        float kt_ = sK[s][i] * expf(-wcs1);
        float bb  = sK[s][i] * expf(wcc - wcs1);
        sR[s][i] = rt_;
        sW[s][i] = kt_;
        sK[s][i] = bb;
        rt[base + (size_t)s * KD_ + i] = rt_;
    }
    if (tid < 64) Dc[(size_t)bid * 64 + tid] = expf(wc[CC_][tid]);
    __syncthreads();

    {
        // score A[tau][sig]: K-index rotated per lane (i = (i0+s0)&63) so the
        // 8 row-reads per group cover distinct banks (was 4-way conflict).
        int tau = tid >> 3, s0 = (tid & 7) * 4;
        float a0 = 0, a1 = 0, a2 = 0, a3 = 0;
        for (int i0 = 0; i0 < 64; i0 += 4) {
            int i = (i0 + s0) & 63;
            float4 rr = *(const float4*)&sR[tau][i];
            float4 k0v = *(const float4*)&sW[s0 + 0][i];
            float4 k1v = *(const float4*)&sW[s0 + 1][i];
            float4 k2v = *(const float4*)&sW[s0 + 2][i];
            float4 k3v = *(const float4*)&sW[s0 + 3][i];
            a0 += rr.x * k0v.x + rr.y * k0v.y + rr.z * k0v.z + rr.w * k0v.w;
            a1 += rr.x * k1v.x + rr.y * k1v.y + rr.z * k1v.z + rr.w * k1v.w;
            a2 += rr.x * k2v.x + rr.y * k2v.y + rr.z * k2v.z + rr.w * k2v.w;
            a3 += rr.x * k3v.x + rr.y * k3v.y + rr.z * k3v.z + rr.w * k3v.w;
        }
        sA[tau][s0 + 0] = (s0 + 0 < tau) ? a0 : ((s0 + 0 == tau) ? diag[tau] : 0.f);
        sA[tau][s0 + 1] = (s0 + 1 < tau) ? a1 : ((s0 + 1 == tau) ? diag[tau] : 0.f);
        sA[tau][s0 + 2] = (s0 + 2 < tau) ? a2 : ((s0 + 2 == tau) ? diag[tau] : 0.f);
        sA[tau][s0 + 3] = (s0 + 3 < tau) ? a3 : ((s0 + 3 == tau) ? diag[tau] : 0.f);
    }
    __syncthreads();

    {
        int tau = tid >> 3, j0 = (tid & 7) * 8;
        float o_[8] __attribute__((aligned(16))) = {};
        for (int s = 0; s < CC_; ++s) {
            float a = sA[tau][s];
            #pragma unroll
            for (int q = 0; q < 8; ++q) o_[q] += a * sV[s][j0 + q];
        }
        size_t ob = base + (size_t)tau * KD_ + j0;
        *(float4*)&ointra[ob]     = *(float4*)&o_[0];
        *(float4*)&ointra[ob + 4] = *(float4*)&o_[4];
    }
    {
        int i = tid >> 2, j0 = (tid & 3) * 16;
        float bacc[16] __attribute__((aligned(16))) = {};
        for (int s = 0; s < CC_; ++s) {
            float bi = sK[s][i];
            #pragma unroll
            for (int q = 0; q < 16; ++q) bacc[q] += bi * sV[s][j0 + q];
        }
        size_t bb = ((size_t)bid << 12) + i * 64 + j0;
        *(float4*)&Bc[bb + 0]  = *(float4*)&bacc[0];
        *(float4*)&Bc[bb + 4]  = *(float4*)&bacc[4];
        *(float4*)&Bc[bb + 8]  = *(float4*)&bacc[8];
        *(float4*)&Bc[bb + 12] = *(float4*)&bacc[12];
    }
}

// ---------------------------------------------------------------------------
__global__ __launch_bounds__(256) void scan_chunkB(float* BS, const float* __restrict__ Dc) {
    int g = blockIdx.x * 256 + threadIdx.x;
    int bh = g >> 12, ij = g & 4095, i = ij >> 6;
    float S = 0.f;
    size_t base = ((size_t)bh << 17) + ij;
    for (int c = 0; c < NC_; ++c) {
        size_t idx = base + ((size_t)c << 12);
        float bv = BS[idx];
        float d = Dc[(size_t)(bh * NC_ + c) * 64 + i];
        BS[idx] = S;
        S = d * S + bv;
    }
}

// ---------------------------------------------------------------------------
__global__ __launch_bounds__(256) void scan_chunkC(const float* __restrict__ rt,
                                                   const float* __restrict__ BS,
                                                   float* o) {
    __shared__ float sS[64][64];
    __shared__ float sRt[CC_][68];
    int bid = blockIdx.x;
    int bh = bid >> 5, c = bid & (NC_ - 1);
    int b = bh >> 4, h = bh & 15;
    int tid = threadIdx.x;
    size_t sbase = ((size_t)bid) << 12;
    for (int q = tid; q < 1024; q += 256)
        *(float4*)&sS[q >> 4][(q & 15) << 2] = *(const float4*)&BS[sbase + (q << 2)];
    size_t base = ((size_t)(b * T_ + c * CC_)) * KD_ + h * 64;
    for (int q = tid; q < CC_ * 16; q += 256) {
        int row = q >> 4, col4 = (q & 15) << 2;
        *(float4*)&sRt[row][col4] = *(const float4*)&rt[base + (size_t)row * KD_ + col4];
    }
    __syncthreads();
    int tau = tid >> 3, j0 = (tid & 7) * 8;
    size_t obase = base + (size_t)tau * KD_ + j0;
    float acc[8] __attribute__((aligned(16)));
    *(float4*)&acc[0] = *(const float4*)&o[obase];
    *(float4*)&acc[4] = *(const float4*)&o[obase + 4];
    for (int i = 0; i < 64; ++i) {
        float a = sRt[tau][i];
        #pragma unroll
        for (int q = 0; q < 8; ++q) acc[q] += a * sS[i][j0 + q];
    }
    *(float4*)&o[obase]     = *(float4*)&acc[0];
    *(float4*)&o[obase + 4] = *(float4*)&acc[4];
}

// ---------------------------------------------------------------------------
// Per-head LN + swish gate -> tiled bf16 A-layout (K=1024, KB=32)
__global__ __launch_bounds__(256) void lngate_kernel(const float* __restrict__ o,
                                                     const float* __restrict__ g,
                                                     const float* __restrict__ lw,
                                                     const float* __restrict__ lb,
                                                     ushort* __restrict__ outt) {
    int rr = blockIdx.x * 4 + (threadIdx.x >> 6);   // (bt*16 + h)
    int c = threadIdx.x & 63;
    size_t idx = (size_t)rr * 64 + c;
    float oc = o[idx];
    float s = oc;
    #pragma unroll
    for (int m = 32; m >= 1; m >>= 1) s += __shfl_xor(s, m, 64);
    float mean = s * (1.f / 64.f);
    float dx = oc - mean;
    float s2 = dx * dx;
    #pragma unroll
    for (int m = 32; m >= 1; m >>= 1) s2 += __shfl_xor(s2, m, 64);
    float var = s2 * (1.f / 64.f);
    float on = dx * rsqrtf(var + 1e-5f) * lw[c] + lb[c];
    float gv = g[idx];
    float val = on * gv / (1.f + expf(-gv));
    int mrow = rr >> 4;
    int col = ((rr & 15) << 6) + c;
    int rb = mrow >> 7, kb = col >> 5, gg = (col >> 3) & 3;
    outt[(((size_t)(rb * 32 + kb)) << 12) + ((gg << 7) + (mrow & 127)) * 8 + (col & 7)] = bf16r(val);
}

// ---------------------------------------------------------------------------
extern "C" void kernel_launch(void* const* d_in, const int* in_sizes, int n_in,
                              void* d_out, int out_size, void* d_ws, size_t ws_size,
                              hipStream_t stream) {
    const float* x     = (const float*)d_in[0];
    const float* mu_x  = (const float*)d_in[1];
    const float* Wx1   = (const float*)d_in[2];
    const float* Wx2   = (const float*)d_in[3];
    const float* xbias = (const float*)d_in[4];
    const float* Wr    = (const float*)d_in[5];
    const float* Wk    = (const float*)d_in[6];
    const float* Wv    = (const float*)d_in[7];
    const float* Ww_a  = (const float*)d_in[8];
    const float* Ww_b  = (const float*)d_in[9];
    const float* bw    = (const float*)d_in[10];
    const float* Wg_a  = (const float*)d_in[11];
    const float* Wg_b  = (const float*)d_in[12];
    const float* bg    = (const float*)d_in[13];
    const float* bonus = (const float*)d_in[14];
    const float* ln_w  = (const float*)d_in[15];
    const float* ln_b  = (const float*)d_in[16];
    const float* Wo    = (const float*)d_in[17];
    float* out = (float*)d_out;

    // workspace layout (float units), with overlays (see launch order)
    float* ws   = (float*)d_ws;
    float* xm   = ws;                               // 4M floats: xmt_r|xmt_k; later gt
    float* lr   = xm   + (size_t)M_ * H_;           // M_*320
    float* hidw = lr   + (size_t)M_ * 320;          // M_*64
    float* hidg = hidw + (size_t)M_ * 64;           // M_*64
    float* rb_  = hidg + (size_t)M_ * 64;           // M_*KD_ ; xm_w spans rb_..kb_
    float* kb_  = rb_  + (size_t)M_ * KD_;
    float* vb_  = kb_  + (size_t)M_ * KD_;          // xm_g spans vb_..db_
    float* db_  = vb_  + (size_t)M_ * KD_;
    float* gb_  = db_  + (size_t)M_ * KD_;
    float* ob_  = gb_  + (size_t)M_ * KD_;
    float* BS   = ob_  + (size_t)M_ * KD_;          // 4M floats: splitk part | xmt_v | scan B/S
    float* Dc   = BS   + (size_t)1024 * 4096;       // 1024*64
    float* wend = Dc + (size_t)1024 * 64;
    // bf16 overlays (ushort units)
    ushort* xmt_r = (ushort*)xm;                            // 8 MB
    ushort* xmt_k = (ushort*)(xm + (size_t)M_ * H_ / 2);    // 8 MB
    ushort* xmt_v = (ushort*)(BS + 1310720);                // 8 MB (past 4MB splitk part)
    float*  xm_w  = rb_;                                    // 16 MB fp32
    float*  xm_g  = vb_;                                    // 16 MB fp32
    ushort* gt    = (ushort*)xm;                            // 4 MB
    ushort* Wx1t  = (ushort*)wend;                          // 2048*320
    ushort* Wrt   = Wx1t + (size_t)H_ * 320;
    ushort* Wkt   = Wrt  + (size_t)H_ * KD_;
    ushort* Wvt   = Wkt  + (size_t)H_ * KD_;
    ushort* Wot   = Wvt  + (size_t)H_ * KD_;                // 1024*2048

    dim3 blk(256);
    const int elems8 = M_ * H_ / 8;

    // 0. weight conversions (tiled bf16)
    convert_w<<<dim3(320 / 64, H_ / 32), blk, 0, stream>>>(Wx1, Wx1t, H_, 320);
    convert_w<<<dim3(KD_ / 64, H_ / 32), blk, 0, stream>>>(Wr, Wrt, H_, KD_);
    convert_w<<<dim3(KD_ / 64, H_ / 32), blk, 0, stream>>>(Wk, Wkt, H_, KD_);
    convert_w<<<dim3(KD_ / 64, H_ / 32), blk, 0, stream>>>(Wv, Wvt, H_, KD_);
    convert_w<<<dim3(H_ / 64, KD_ / 32), blk, 0, stream>>>(Wo, Wot, KD_, H_);

    // 1. lr = tanh((x + delta*mu_x) @ Wx1)   [bf16 MFMA]; staging in xm region
    mix_mu_t<<<elems8 / 256, blk, 0, stream>>>(x, mu_x, (ushort*)xm);
    gemm_bf16t<1><<<dim3(320 / 64, M_ / 128), blk, 0, stream>>>((ushort*)xm, Wx1t, lr, H_, 320);

    // 2. fused 5-branch mus-GEMM + lerp (writes all xm variants)
    musgemm5_kernel<<<dim3(H_ / 64, M_ / 64), blk, 0, stream>>>(x, lr, Wx2, xbias,
                                                                xmt_r, xm_w, xmt_k, xmt_v, xm_g);

    // 3. LoRA down-projections (split-K, fp32) + tanh reduce
    gemm_f32_splitk<<<dim3(8, M_ / 64), blk, 0, stream>>>(xm_w, Ww_a, BS);
    reduce_tanh<<<128, blk, 0, stream>>>(BS, hidw);
    gemm_f32_splitk<<<dim3(8, M_ / 64), blk, 0, stream>>>(xm_g, Wg_a, BS);
    reduce_tanh<<<128, blk, 0, stream>>>(BS, hidg);

    // 4. LoRA up-projections (fp32): log-decay and raw gate
    gemm_f32<3><<<dim3(KD_ / 64, M_ / 64), blk, 0, stream>>>(hidw, Ww_b, bw, db_, 64, 64, KD_, KD_);
    gemm_f32<2><<<dim3(KD_ / 64, M_ / 64), blk, 0, stream>>>(hidg, Wg_b, bg, gb_, 64, 64, KD_, KD_);

    // 5. r/k/v projections [bf16 MFMA] (overwrite consumed xm_w/xm_g regions)
    gemm_bf16t<0><<<dim3(KD_ / 64, M_ / 128), blk, 0, stream>>>(xmt_r, Wrt, rb_, H_, KD_);
    gemm_bf16t<0><<<dim3(KD_ / 64, M_ / 128), blk, 0, stream>>>(xmt_k, Wkt, kb_, H_, KD_);
    gemm_bf16t<0><<<dim3(KD_ / 64, M_ / 128), blk, 0, stream>>>(xmt_v, Wvt, vb_, H_, KD_);

    // 6. chunk-parallel scan (fp32)
    scan_chunkA<<<B_ * NH_ * NC_, blk, 0, stream>>>(rb_, kb_, vb_, db_, bonus,
                                                    rb_ /*rt in place*/, ob_, BS, Dc);
    scan_chunkB<<<(B_ * NH_ * 4096) / 256, blk, 0, stream>>>(BS, Dc);
    scan_chunkC<<<B_ * NH_ * NC_, blk, 0, stream>>>(rb_, BS, ob_);

    // 7. LN + swish gate -> tiled bf16 (xm region free again)
    lngate_kernel<<<(M_ * NH_) / 4, blk, 0, stream>>>(ob_, gb_, ln_w, ln_b, gt);

    // 8. out = gated @ Wo  [bf16 MFMA]
    gemm_bf16t<0><<<dim3(H_ / 64, M_ / 128), blk, 0, stream>>>(gt, Wot, out, KD_, H_);
}

// Round 7
// 337.976 us; speedup vs baseline: 7.7095x; 1.0567x over previous
//
#include <hip/hip_runtime.h>
#include <hip/hip_bf16.h>

#define H_    2048
#define NH_   16
#define KD_   1024
#define DK_   64
#define T_    1024
#define B_    2
#define M_    (B_*T_)     // 2048 rows
#define RL_   64
#define CC_   32          // scan chunk length
#define NC_   (T_/CC_)    // 32 chunks per sequence

typedef short bf16x8 __attribute__((ext_vector_type(8)));   // 8 bf16 (4 VGPR)
typedef float f32x4  __attribute__((ext_vector_type(4)));   // MFMA acc

__device__ __forceinline__ ushort bf16r(float f) {          // RNE fp32->bf16
    union { float f; unsigned u; } v; v.f = f;
    return (ushort)((v.u + 0x7FFF + ((v.u >> 16) & 1)) >> 16);
}

// ---------------------------------------------------------------------------
// Tiled bf16 layouts:
//  A-tiles (BM=128, BK=32): tile id (rb*KB + kb), 4096 bf16/tile,
//    elem (r,k): off = (g*128 + r)*8 + (k&7),  g=(k>>3)&3
//  B-tiles (BN=64, BK=32): tile id (nb*KB + kb), 2048 bf16/tile,
//    elem (c,k): off = (g*64 + c)*8 + (k&7)
// ---------------------------------------------------------------------------

// xx = x + (shift(x)-x)*mu_x  -> tiled bf16 A-layout (chunk per thread)
__global__ __launch_bounds__(256) void mix_mu_t(const float* __restrict__ x,
                                                const float* __restrict__ mu,
                                                ushort* __restrict__ At) {
    int c = blockIdx.x * 256 + threadIdx.x;       // chunk id 0..M_*H_/8
    int bt = c >> 8, k8 = c & 255;
    int k = k8 << 3;
    int t = bt & (T_ - 1);
    const float* xp = &x[(size_t)bt * H_ + k];
    float4 xa = *(const float4*)xp;
    float4 xb = *(const float4*)(xp + 4);
    float4 sa = make_float4(0,0,0,0), sb = make_float4(0,0,0,0);
    if (t > 0) { sa = *(const float4*)(xp - H_); sb = *(const float4*)(xp - H_ + 4); }
    float4 ma = *(const float4*)&mu[k];
    float4 mb = *(const float4*)&mu[k + 4];
    ushort o[8];
    o[0] = bf16r(xa.x + (sa.x - xa.x) * ma.x);
    o[1] = bf16r(xa.y + (sa.y - xa.y) * ma.y);
    o[2] = bf16r(xa.z + (sa.z - xa.z) * ma.z);
    o[3] = bf16r(xa.w + (sa.w - xa.w) * ma.w);
    o[4] = bf16r(xb.x + (sb.x - xb.x) * mb.x);
    o[5] = bf16r(xb.y + (sb.y - xb.y) * mb.y);
    o[6] = bf16r(xb.z + (sb.z - xb.z) * mb.z);
    o[7] = bf16r(xb.w + (sb.w - xb.w) * mb.w);
    int rb = bt >> 7, kb = k8 >> 2, g = k8 & 3, r = bt & 127;
    *(uint4*)&At[(((size_t)(rb * 64 + kb)) << 12) + ((g << 7) + r) * 8] = *(uint4*)o;
}

// ---------------------------------------------------------------------------
// W [K][N] fp32 -> tiled bf16 B-layout (per 32x64 tile block, LDS transpose)
__global__ __launch_bounds__(256) void convert_w(const float* __restrict__ W,
                                                 ushort* __restrict__ Wt,
                                                 int K, int N) {
    __shared__ float s[32][68];
    int kb = blockIdx.y, nb = blockIdx.x;
    int t = threadIdx.x;
    #pragma unroll
    for (int i = 0; i < 2; ++i) {
        int q = t + i * 256;                       // 0..511 float4s
        int k = q >> 4, c4 = (q & 15) << 2;
        *(float4*)&s[k][c4] = *(const float4*)&W[(size_t)(kb * 32 + k) * N + nb * 64 + c4];
    }
    __syncthreads();
    int g = t >> 6, c = t & 63;
    ushort o[8];
    #pragma unroll
    for (int e = 0; e < 8; ++e) o[e] = bf16r(s[g * 8 + e][c]);
    *(uint4*)&Wt[((size_t)(nb * (K >> 5) + kb)) * 2048 + t * 8] = *(uint4*)o;
}

// ---------------------------------------------------------------------------
// bf16 MFMA GEMM: C[M][ldc] = epi(A @ B), A tiled bf16 (BM=128), B tiled (BN=64).
// 256 thr = 4 waves (2x2), wave = 64x32 out = 4x2 frags of 16x16, BK=32.
// EPI: 0 = none, 1 = tanh
template<int EPI>
__global__ __launch_bounds__(256) void gemm_bf16t(const ushort* __restrict__ At,
                                                  const ushort* __restrict__ Bt,
                                                  float* __restrict__ C,
                                                  int K, int ldc) {
    __shared__ ushort Alds[4096];
    __shared__ ushort Blds[2048];
    int tid = threadIdx.x;
    int w = tid >> 6, l = tid & 63;
    int KB = K >> 5;
    const ushort* Ag = At + (size_t)blockIdx.y * KB * 4096 + tid * 8;
    const ushort* Bg = Bt + (size_t)blockIdx.x * KB * 2048 + tid * 8;
    int wr = (w >> 1) << 6, wc = (w & 1) << 5;
    int a_off = (((l >> 4) << 7) + wr + (l & 15)) << 3;   // (g*128 + row)*8
    int b_off = (((l >> 4) << 6) + wc + (l & 15)) << 3;   // (g*64 + col)*8
    f32x4 acc[8] = {};
    uint4 a0 = *(const uint4*)(Ag);
    uint4 a1 = *(const uint4*)(Ag + 2048);
    uint4 b0 = *(const uint4*)(Bg);
    for (int kt = 0; kt < KB; ++kt) {
        __syncthreads();                       // prior ds_reads done
        *(uint4*)&Alds[tid * 8] = a0;
        *(uint4*)&Alds[tid * 8 + 2048] = a1;
        *(uint4*)&Blds[tid * 8] = b0;
        __syncthreads();
        if (kt + 1 < KB) {                     // prefetch next K-tile
            Ag += 4096; Bg += 2048;
            a0 = *(const uint4*)(Ag);
            a1 = *(const uint4*)(Ag + 2048);
            b0 = *(const uint4*)(Bg);
        }
        bf16x8 af0 = *(const bf16x8*)&Alds[a_off];
        bf16x8 af1 = *(const bf16x8*)&Alds[a_off + 128];
        bf16x8 af2 = *(const bf16x8*)&Alds[a_off + 256];
        bf16x8 af3 = *(const bf16x8*)&Alds[a_off + 384];
        bf16x8 bf0 = *(const bf16x8*)&Blds[b_off];
        bf16x8 bf1 = *(const bf16x8*)&Blds[b_off + 128];
        acc[0] = __builtin_amdgcn_mfma_f32_16x16x32_bf16(af0, bf0, acc[0], 0, 0, 0);
        acc[1] = __builtin_amdgcn_mfma_f32_16x16x32_bf16(af0, bf1, acc[1], 0, 0, 0);
        acc[2] = __builtin_amdgcn_mfma_f32_16x16x32_bf16(af1, bf0, acc[2], 0, 0, 0);
        acc[3] = __builtin_amdgcn_mfma_f32_16x16x32_bf16(af1, bf1, acc[3], 0, 0, 0);
        acc[4] = __builtin_amdgcn_mfma_f32_16x16x32_bf16(af2, bf0, acc[4], 0, 0, 0);
        acc[5] = __builtin_amdgcn_mfma_f32_16x16x32_bf16(af2, bf1, acc[5], 0, 0, 0);
        acc[6] = __builtin_amdgcn_mfma_f32_16x16x32_bf16(af3, bf0, acc[6], 0, 0, 0);
        acc[7] = __builtin_amdgcn_mfma_f32_16x16x32_bf16(af3, bf1, acc[7], 0, 0, 0);
    }
    int row0 = (blockIdx.y << 7) + wr + ((l >> 4) << 2);
    int col0 = (blockIdx.x << 6) + wc + (l & 15);
    #pragma unroll
    for (int fr = 0; fr < 4; ++fr)
        #pragma unroll
        for (int fc = 0; fc < 2; ++fc) {
            f32x4 v = acc[fr * 2 + fc];
            #pragma unroll
            for (int q = 0; q < 4; ++q) {
                float o = v[q];
                if (EPI == 1) o = tanhf(o);
                C[(size_t)(row0 + fr * 16 + q) * ldc + col0 + fc * 16] = o;
            }
        }
}

// ---------------------------------------------------------------------------
// Fused 5-branch mus-GEMM + lerp, transposed LDS staging (bank-conflict-free):
// sLT[k][bt], sWT[k][h]; outer-product inner loop reads contiguous float4s.
__global__ __launch_bounds__(256) void musgemm5_kernel(const float* __restrict__ x,
                                                       const float* __restrict__ lr,
                                                       const float* __restrict__ Wx2,
                                                       const float* __restrict__ xbias,
                                                       ushort* __restrict__ xmt_r,
                                                       float*  __restrict__ xm_w,
                                                       ushort* __restrict__ xmt_k,
                                                       ushort* __restrict__ xmt_v,
                                                       float*  __restrict__ xm_g) {
    __shared__ float sX[65][68];   // rows row0-1 .. row0+63
    __shared__ float sLT[64][68];  // [k][bt]
    __shared__ float sWT[64][68];  // [k][h]
    int tid = threadIdx.x;
    int tx = tid & 15, ty = tid >> 4;
    int col0 = blockIdx.x * 64;    // h
    int row0 = blockIdx.y * 64;    // bt
    for (int q = tid; q < 65 * 16; q += 256) {
        int rr = q >> 4, c4 = (q & 15) << 2;
        int gr = row0 + rr - 1;
        float4 v = make_float4(0.f, 0.f, 0.f, 0.f);
        if (gr >= 0) v = *(const float4*)&x[(size_t)gr * H_ + col0 + c4];
        *(float4*)&sX[rr][c4] = v;
    }
    int kcol = col0 + (tx << 2);
    int lrow = tid >> 2;                 // staging: row 0..63
    int lk   = (tid & 3) << 2;           // k base 0..12
    #pragma unroll
    for (int b = 0; b < 5; ++b) {
        __syncthreads();   // prior-branch LDS reads done (and sX staged, b==0)
        #pragma unroll
        for (int pass = 0; pass < 4; ++pass) {
            int kk = lk + pass * 16;
            float4 lv = *(const float4*)&lr[(size_t)(row0 + lrow) * 320 + b * 64 + kk];
            float4 wv = *(const float4*)&Wx2[(size_t)(col0 + lrow) * 320 + b * 64 + kk];
            sLT[kk + 0][lrow] = lv.x; sLT[kk + 1][lrow] = lv.y;
            sLT[kk + 2][lrow] = lv.z; sLT[kk + 3][lrow] = lv.w;
            sWT[kk + 0][lrow] = wv.x; sWT[kk + 1][lrow] = wv.y;
            sWT[kk + 2][lrow] = wv.z; sWT[kk + 3][lrow] = wv.w;
        }
        __syncthreads();
        float acc[4][4] = {};
        #pragma unroll 4
        for (int k = 0; k < 64; ++k) {
            float4 a = *(const float4*)&sLT[k][ty << 2];
            float4 bb = *(const float4*)&sWT[k][tx << 2];
            float aa[4] = {a.x, a.y, a.z, a.w};
            float bv_[4] = {bb.x, bb.y, bb.z, bb.w};
            #pragma unroll
            for (int i = 0; i < 4; ++i)
                #pragma unroll
                for (int j = 0; j < 4; ++j)
                    acc[i][j] = fmaf(aa[i], bv_[j], acc[i][j]);
        }
        float4 bias4 = *(const float4*)&xbias[b * H_ + kcol];
        float bv[4] = {bias4.x, bias4.y, bias4.z, bias4.w};
        #pragma unroll
        for (int i = 0; i < 4; ++i) {
            int sr = (ty << 2) + i + 1;
            int r = row0 + (ty << 2) + i;
            int t = r & (T_ - 1);
            float4 xv = *(const float4*)&sX[sr][tx << 2];
            float4 sh = make_float4(0.f, 0.f, 0.f, 0.f);
            if (t > 0) sh = *(const float4*)&sX[sr - 1][tx << 2];
            float o0 = xv.x + (sh.x - xv.x) * (acc[i][0] + bv[0]);
            float o1 = xv.y + (sh.y - xv.y) * (acc[i][1] + bv[1]);
            float o2 = xv.z + (sh.z - xv.z) * (acc[i][2] + bv[2]);
            float o3 = xv.w + (sh.w - xv.w) * (acc[i][3] + bv[3]);
            if (b == 0 || b == 2 || b == 3) {
                ushort* dst = (b == 0) ? xmt_r : (b == 2) ? xmt_k : xmt_v;
                int rb = r >> 7, kb = kcol >> 5, g = (kcol >> 3) & 3, hf = (kcol >> 2) & 1;
                ushort4 pk; pk.x = bf16r(o0); pk.y = bf16r(o1); pk.z = bf16r(o2); pk.w = bf16r(o3);
                *(ushort4*)&dst[(((size_t)(rb * 64 + kb)) << 12) + ((g << 7) + (r & 127)) * 8 + hf * 4] = pk;
            } else {
                float* dst = (b == 1) ? xm_w : xm_g;
                float4 o; o.x = o0; o.y = o1; o.z = o2; o.w = o3;
                *(float4*)&dst[(size_t)r * H_ + kcol] = o;
            }
        }
    }
}

// ---------------------------------------------------------------------------
// fp32 GEMM (LoRA up paths). EPI: 1 = tanh, 2 = +bias, 3 = -exp(v+bias)
template<int EPI>
__global__ __launch_bounds__(256) void gemm_f32(const float* __restrict__ A,
                                                const float* __restrict__ W,
                                                const float* __restrict__ bias,
                                                float* __restrict__ C,
                                                int K, int lda, int ldb, int ldc) {
    __shared__ float As[16][68];
    __shared__ float Bs[16][68];
    int tid = threadIdx.x;
    int tx = tid & 15, ty = tid >> 4;
    int row0 = blockIdx.y * 64, col0 = blockIdx.x * 64;
    int am = tid >> 2, ak = (tid & 3) << 2;
    int bk = tid >> 4, bn = (tid & 15) << 2;
    float acc[4][4] = {};
    float4 av = *(const float4*)&A[(size_t)(row0 + am) * lda + ak];
    float4 bv = *(const float4*)&W[(size_t)bk * ldb + col0 + bn];
    for (int k0 = 0; k0 < K; k0 += 16) {
        __syncthreads();
        As[ak + 0][am] = av.x; As[ak + 1][am] = av.y;
        As[ak + 2][am] = av.z; As[ak + 3][am] = av.w;
        *(float4*)&Bs[bk][bn] = bv;
        __syncthreads();
        if (k0 + 16 < K) {
            av = *(const float4*)&A[(size_t)(row0 + am) * lda + k0 + 16 + ak];
            bv = *(const float4*)&W[(size_t)(k0 + 16 + bk) * ldb + col0 + bn];
        }
        #pragma unroll
        for (int kk = 0; kk < 16; ++kk) {
            float4 a = *(const float4*)&As[kk][ty << 2];
            float4 b = *(const float4*)&Bs[kk][tx << 2];
            float aa[4] = {a.x, a.y, a.z, a.w};
            float bb[4] = {b.x, b.y, b.z, b.w};
            #pragma unroll
            for (int i = 0; i < 4; ++i)
                #pragma unroll
                for (int j = 0; j < 4; ++j)
                    acc[i][j] = fmaf(aa[i], bb[j], acc[i][j]);
        }
    }
    #pragma unroll
    for (int i = 0; i < 4; ++i) {
        int r = row0 + (ty << 2) + i;
        #pragma unroll
        for (int j = 0; j < 4; ++j) {
            int c = col0 + (tx << 2) + j;
            float v = acc[i][j];
            if (EPI == 2 || EPI == 3) v += bias[c];
            if (EPI == 1) v = tanhf(v);
            if (EPI == 3) v = -expf(v);   // store LOG decay
            C[(size_t)r * ldc + c] = v;
        }
    }
}

// ---------------------------------------------------------------------------
// Split-K fp32 GEMM for LoRA down-proj: A[2048][2048] @ W[2048][64].
__global__ __launch_bounds__(256) void gemm_f32_splitk(const float* __restrict__ A,
                                                       const float* __restrict__ W,
                                                       float* __restrict__ part) {
    __shared__ float As[16][68];
    __shared__ float Bs[16][68];
    int tid = threadIdx.x;
    int tx = tid & 15, ty = tid >> 4;
    int row0 = blockIdx.y * 64;
    int kbase = blockIdx.x * 256;
    int am = tid >> 2, ak = (tid & 3) << 2;
    int bk = tid >> 4, bn = (tid & 15) << 2;
    float acc[4][4] = {};
    float4 av = *(const float4*)&A[(size_t)(row0 + am) * H_ + kbase + ak];
    float4 bv = *(const float4*)&W[(size_t)(kbase + bk) * 64 + bn];
    for (int k0 = 0; k0 < 256; k0 += 16) {
        __syncthreads();
        As[ak + 0][am] = av.x; As[ak + 1][am] = av.y;
        As[ak + 2][am] = av.z; As[ak + 3][am] = av.w;
        *(float4*)&Bs[bk][bn] = bv;
        __syncthreads();
        if (k0 + 16 < 256) {
            av = *(const float4*)&A[(size_t)(row0 + am) * H_ + kbase + k0 + 16 + ak];
            bv = *(const float4*)&W[(size_t)(kbase + k0 + 16 + bk) * 64 + bn];
        }
        #pragma unroll
        for (int kk = 0; kk < 16; ++kk) {
            float4 a = *(const float4*)&As[kk][ty << 2];
            float4 b = *(const float4*)&Bs[kk][tx << 2];
            float aa[4] = {a.x, a.y, a.z, a.w};
            float bb[4] = {b.x, b.y, b.z, b.w};
            #pragma unroll
            for (int i = 0; i < 4; ++i)
                #pragma unroll
                for (int j = 0; j < 4; ++j)
                    acc[i][j] = fmaf(aa[i], bb[j], acc[i][j]);
        }
    }
    float* pc = part + (size_t)blockIdx.x * (M_ * 64);
    #pragma unroll
    for (int i = 0; i < 4; ++i) {
        int r = row0 + (ty << 2) + i;
        #pragma unroll
        for (int j = 0; j < 4; ++j)
            pc[(size_t)r * 64 + (tx << 2) + j] = acc[i][j];
    }
}

// hid = tanh(sum_kc part[kc])   (2048x64, float4 per thread)
__global__ __launch_bounds__(256) void reduce_tanh(const float* __restrict__ part,
                                                   float* __restrict__ hid) {
    int i = blockIdx.x * 256 + threadIdx.x;       // 32768 float4s
    const float4* p = (const float4*)part;
    float4 s = p[i];
    #pragma unroll
    for (int kc = 1; kc < 8; ++kc) {
        float4 v = p[i + kc * 32768];
        s.x += v.x; s.y += v.y; s.z += v.z; s.w += v.w;
    }
    s.x = tanhf(s.x); s.y = tanhf(s.y); s.z = tanhf(s.z); s.w = tanhf(s.w);
    ((float4*)hid)[i] = s;
}

// ---------------------------------------------------------------------------
// Chunked scan, phase A.
__global__ __launch_bounds__(256) void scan_chunkA(const float* r, const float* k,
                                                   const float* v, const float* ld,
                                                   const float* u,
                                                   float* rt, float* ointra,
                                                   float* Bc, float* Dc) {
    __shared__ float sR[CC_][68], sK[CC_][68], sV[CC_][68], sW[CC_][68];
    __shared__ float wc[CC_ + 1][64];
    __shared__ float sA[CC_][36];
    __shared__ float diag[CC_];
    __shared__ float sU[64];
    int bid = blockIdx.x;
    int bh = bid >> 5, c = bid & (NC_ - 1);
    int b = bh >> 4, h = bh & 15;
    int tid = threadIdx.x;
    size_t base = ((size_t)(b * T_ + c * CC_)) * KD_ + h * 64;

    for (int q = tid; q < CC_ * 16; q += 256) {
        int row = q >> 4, col4 = (q & 15) << 2;
        size_t gi = base + (size_t)row * KD_ + col4;
        *(float4*)&sR[row][col4] = *(const float4*)&r[gi];
        *(float4*)&sK[row][col4] = *(const float4*)&k[gi];
        *(float4*)&sV[row][col4] = *(const float4*)&v[gi];
        *(float4*)&sW[row][col4] = *(const float4*)&ld[gi];
    }
    if (tid < 64) sU[tid] = u[h * 64 + tid];
    __syncthreads();

    if (tid < 64) {
        float acc = 0.f;
        wc[0][tid] = 0.f;
        #pragma unroll
        for (int s = 0; s < CC_; ++s) { acc += sW[s][tid]; wc[s + 1][tid] = acc; }
    }
    {
        int tau = tid >> 3, g = tid & 7;
        float p = 0.f;
        #pragma unroll
        for (int q = 0; q < 8; ++q) {
            int i = g * 8 + q;
            p += sR[tau][i] * sU[i] * sK[tau][i];
        }
        p += __shfl_xor(p, 1, 64); p += __shfl_xor(p, 2, 64); p += __shfl_xor(p, 4, 64);
        if (g == 0) diag[tau] = p;
    }
    __syncthreads();

    for (int q = tid; q < CC_ * 64; q += 256) {
        int s = q >> 6, i = q & 63;
        float wcs  = wc[s][i];
        float wcs1 = wc[s + 1][i];
        float wcc  = wc[CC_][i];
        float rt_ = sR[s][i] * expf(wcs);
        float kt_ = sK[s][i] * expf(-wcs1);
        float bb  = sK[s][i] * expf(wcc - wcs1);
        sR[s][i] = rt_;
        sW[s][i] = kt_;
        sK[s][i] = bb;
        rt[base + (size_t)s * KD_ + i] = rt_;
    }
    if (tid < 64) Dc[(size_t)bid * 64 + tid] = expf(wc[CC_][tid]);
    __syncthreads();

    {
        // score A[tau][sig]: K-index rotated per lane (i = (i0+s0)&63) so the
        // 8 row-reads per group cover distinct banks.
        int tau = tid >> 3, s0 = (tid & 7) * 4;
        float a0 = 0, a1 = 0, a2 = 0, a3 = 0;
        for (int i0 = 0; i0 < 64; i0 += 4) {
            int i = (i0 + s0) & 63;
            float4 rr = *(const float4*)&sR[tau][i];
            float4 k0v = *(const float4*)&sW[s0 + 0][i];
            float4 k1v = *(const float4*)&sW[s0 + 1][i];
            float4 k2v = *(const float4*)&sW[s0 + 2][i];
            float4 k3v = *(const float4*)&sW[s0 + 3][i];
            a0 += rr.x * k0v.x + rr.y * k0v.y + rr.z * k0v.z + rr.w * k0v.w;
            a1 += rr.x * k1v.x + rr.y * k1v.y + rr.z * k1v.z + rr.w * k1v.w;
            a2 += rr.x * k2v.x + rr.y * k2v.y + rr.z * k2v.z + rr.w * k2v.w;
            a3 += rr.x * k3v.x + rr.y * k3v.y + rr.z * k3v.z + rr.w * k3v.w;
        }
        sA[tau][s0 + 0] = (s0 + 0 < tau) ? a0 : ((s0 + 0 == tau) ? diag[tau] : 0.f);
        sA[tau][s0 + 1] = (s0 + 1 < tau) ? a1 : ((s0 + 1 == tau) ? diag[tau] : 0.f);
        sA[tau][s0 + 2] = (s0 + 2 < tau) ? a2 : ((s0 + 2 == tau) ? diag[tau] : 0.f);
        sA[tau][s0 + 3] = (s0 + 3 < tau) ? a3 : ((s0 + 3 == tau) ? diag[tau] : 0.f);
    }
    __syncthreads();

    {
        int tau = tid >> 3, j0 = (tid & 7) * 8;
        float o_[8] __attribute__((aligned(16))) = {};
        for (int s = 0; s < CC_; ++s) {
            float a = sA[tau][s];
            #pragma unroll
            for (int q = 0; q < 8; ++q) o_[q] += a * sV[s][j0 + q];
        }
        size_t ob = base + (size_t)tau * KD_ + j0;
        *(float4*)&ointra[ob]     = *(float4*)&o_[0];
        *(float4*)&ointra[ob + 4] = *(float4*)&o_[4];
    }
    {
        int i = tid >> 2, j0 = (tid & 3) * 16;
        float bacc[16] __attribute__((aligned(16))) = {};
        for (int s = 0; s < CC_; ++s) {
            float bi = sK[s][i];
            #pragma unroll
            for (int q = 0; q < 16; ++q) bacc[q] += bi * sV[s][j0 + q];
        }
        size_t bb = ((size_t)bid << 12) + i * 64 + j0;
        *(float4*)&Bc[bb + 0]  = *(float4*)&bacc[0];
        *(float4*)&Bc[bb + 4]  = *(float4*)&bacc[4];
        *(float4*)&Bc[bb + 8]  = *(float4*)&bacc[8];
        *(float4*)&Bc[bb + 12] = *(float4*)&bacc[12];
    }
}

// ---------------------------------------------------------------------------
__global__ __launch_bounds__(256) void scan_chunkB(float* BS, const float* __restrict__ Dc) {
    int g = blockIdx.x * 256 + threadIdx.x;
    int bh = g >> 12, ij = g & 4095, i = ij >> 6;
    float S = 0.f;
    size_t base = ((size_t)bh << 17) + ij;
    for (int c = 0; c < NC_; ++c) {
        size_t idx = base + ((size_t)c << 12);
        float bv = BS[idx];
        float d = Dc[(size_t)(bh * NC_ + c) * 64 + i];
        BS[idx] = S;
        S = d * S + bv;
    }
}

// ---------------------------------------------------------------------------
__global__ __launch_bounds__(256) void scan_chunkC(const float* __restrict__ rt,
                                                   const float* __restrict__ BS,
                                                   float* o) {
    __shared__ float sS[64][64];
    __shared__ float sRt[CC_][68];
    int bid = blockIdx.x;
    int bh = bid >> 5, c = bid & (NC_ - 1);
    int b = bh >> 4, h = bh & 15;
    int tid = threadIdx.x;
    size_t sbase = ((size_t)bid) << 12;
    for (int q = tid; q < 1024; q += 256)
        *(float4*)&sS[q >> 4][(q & 15) << 2] = *(const float4*)&BS[sbase + (q << 2)];
    size_t base = ((size_t)(b * T_ + c * CC_)) * KD_ + h * 64;
    for (int q = tid; q < CC_ * 16; q += 256) {
        int row = q >> 4, col4 = (q & 15) << 2;
        *(float4*)&sRt[row][col4] = *(const float4*)&rt[base + (size_t)row * KD_ + col4];
    }
    __syncthreads();
    int tau = tid >> 3, j0 = (tid & 7) * 8;
    size_t obase = base + (size_t)tau * KD_ + j0;
    float acc[8] __attribute__((aligned(16)));
    *(float4*)&acc[0] = *(const float4*)&o[obase];
    *(float4*)&acc[4] = *(const float4*)&o[obase + 4];
    for (int i = 0; i < 64; ++i) {
        float a = sRt[tau][i];
        #pragma unroll
        for (int q = 0; q < 8; ++q) acc[q] += a * sS[i][j0 + q];
    }
    *(float4*)&o[obase]     = *(float4*)&acc[0];
    *(float4*)&o[obase + 4] = *(float4*)&acc[4];
}

// ---------------------------------------------------------------------------
// Per-head LN + swish gate -> tiled bf16 A-layout (K=1024, KB=32)
__global__ __launch_bounds__(256) void lngate_kernel(const float* __restrict__ o,
                                                     const float* __restrict__ g,
                                                     const float* __restrict__ lw,
                                                     const float* __restrict__ lb,
                                                     ushort* __restrict__ outt) {
    int rr = blockIdx.x * 4 + (threadIdx.x >> 6);   // (bt*16 + h)
    int c = threadIdx.x & 63;
    size_t idx = (size_t)rr * 64 + c;
    float oc = o[idx];
    float s = oc;
    #pragma unroll
    for (int m = 32; m >= 1; m >>= 1) s += __shfl_xor(s, m, 64);
    float mean = s * (1.f / 64.f);
    float dx = oc - mean;
    float s2 = dx * dx;
    #pragma unroll
    for (int m = 32; m >= 1; m >>= 1) s2 += __shfl_xor(s2, m, 64);
    float var = s2 * (1.f / 64.f);
    float on = dx * rsqrtf(var + 1e-5f) * lw[c] + lb[c];
    float gv = g[idx];
    float val = on * gv / (1.f + expf(-gv));
    int mrow = rr >> 4;
    int col = ((rr & 15) << 6) + c;
    int rb = mrow >> 7, kb = col >> 5, gg = (col >> 3) & 3;
    outt[(((size_t)(rb * 32 + kb)) << 12) + ((gg << 7) + (mrow & 127)) * 8 + (col & 7)] = bf16r(val);
}

// ---------------------------------------------------------------------------
extern "C" void kernel_launch(void* const* d_in, const int* in_sizes, int n_in,
                              void* d_out, int out_size, void* d_ws, size_t ws_size,
                              hipStream_t stream) {
    const float* x     = (const float*)d_in[0];
    const float* mu_x  = (const float*)d_in[1];
    const float* Wx1   = (const float*)d_in[2];
    const float* Wx2   = (const float*)d_in[3];
    const float* xbias = (const float*)d_in[4];
    const float* Wr    = (const float*)d_in[5];
    const float* Wk    = (const float*)d_in[6];
    const float* Wv    = (const float*)d_in[7];
    const float* Ww_a  = (const float*)d_in[8];
    const float* Ww_b  = (const float*)d_in[9];
    const float* bw    = (const float*)d_in[10];
    const float* Wg_a  = (const float*)d_in[11];
    const float* Wg_b  = (const float*)d_in[12];
    const float* bg    = (const float*)d_in[13];
    const float* bonus = (const float*)d_in[14];
    const float* ln_w  = (const float*)d_in[15];
    const float* ln_b  = (const float*)d_in[16];
    const float* Wo    = (const float*)d_in[17];
    float* out = (float*)d_out;

    // workspace layout (float units), with overlays (see launch order)
    float* ws   = (float*)d_ws;
    float* xm   = ws;                               // 4M floats: xmt_r|xmt_k; later gt
    float* lr   = xm   + (size_t)M_ * H_;           // M_*320
    float* hidw = lr   + (size_t)M_ * 320;          // M_*64
    float* hidg = hidw + (size_t)M_ * 64;           // M_*64
    float* rb_  = hidg + (size_t)M_ * 64;           // M_*KD_ ; xm_w spans rb_..kb_
    float* kb_  = rb_  + (size_t)M_ * KD_;
    float* vb_  = kb_  + (size_t)M_ * KD_;          // xm_g spans vb_..db_
    float* db_  = vb_  + (size_t)M_ * KD_;
    float* gb_  = db_  + (size_t)M_ * KD_;
    float* ob_  = gb_  + (size_t)M_ * KD_;
    float* BS   = ob_  + (size_t)M_ * KD_;          // 4M floats: splitk part | xmt_v | scan B/S
    float* Dc   = BS   + (size_t)1024 * 4096;       // 1024*64
    float* wend = Dc + (size_t)1024 * 64;
    // bf16 overlays (ushort units)
    ushort* xmt_r = (ushort*)xm;                            // 8 MB
    ushort* xmt_k = (ushort*)(xm + (size_t)M_ * H_ / 2);    // 8 MB
    ushort* xmt_v = (ushort*)(BS + 1310720);                // 8 MB (past 4MB splitk part)
    float*  xm_w  = rb_;                                    // 16 MB fp32
    float*  xm_g  = vb_;                                    // 16 MB fp32
    ushort* gt    = (ushort*)xm;                            // 4 MB
    ushort* Wx1t  = (ushort*)wend;                          // 2048*320
    ushort* Wrt   = Wx1t + (size_t)H_ * 320;
    ushort* Wkt   = Wrt  + (size_t)H_ * KD_;
    ushort* Wvt   = Wkt  + (size_t)H_ * KD_;
    ushort* Wot   = Wvt  + (size_t)H_ * KD_;                // 1024*2048

    dim3 blk(256);
    const int elems8 = M_ * H_ / 8;

    // 0. weight conversions (tiled bf16)
    convert_w<<<dim3(320 / 64, H_ / 32), blk, 0, stream>>>(Wx1, Wx1t, H_, 320);
    convert_w<<<dim3(KD_ / 64, H_ / 32), blk, 0, stream>>>(Wr, Wrt, H_, KD_);
    convert_w<<<dim3(KD_ / 64, H_ / 32), blk, 0, stream>>>(Wk, Wkt, H_, KD_);
    convert_w<<<dim3(KD_ / 64, H_ / 32), blk, 0, stream>>>(Wv, Wvt, H_, KD_);
    convert_w<<<dim3(H_ / 64, KD_ / 32), blk, 0, stream>>>(Wo, Wot, KD_, H_);

    // 1. lr = tanh((x + delta*mu_x) @ Wx1)   [bf16 MFMA]; staging in xm region
    mix_mu_t<<<elems8 / 256, blk, 0, stream>>>(x, mu_x, (ushort*)xm);
    gemm_bf16t<1><<<dim3(320 / 64, M_ / 128), blk, 0, stream>>>((ushort*)xm, Wx1t, lr, H_, 320);

    // 2. fused 5-branch mus-GEMM + lerp (writes all xm variants)
    musgemm5_kernel<<<dim3(H_ / 64, M_ / 64), blk, 0, stream>>>(x, lr, Wx2, xbias,
                                                                xmt_r, xm_w, xmt_k, xmt_v, xm_g);

    // 3. LoRA down-projections (split-K, fp32) + tanh reduce
    gemm_f32_splitk<<<dim3(8, M_ / 64), blk, 0, stream>>>(xm_w, Ww_a, BS);
    reduce_tanh<<<128, blk, 0, stream>>>(BS, hidw);
    gemm_f32_splitk<<<dim3(8, M_ / 64), blk, 0, stream>>>(xm_g, Wg_a, BS);
    reduce_tanh<<<128, blk, 0, stream>>>(BS, hidg);

    // 4. LoRA up-projections (fp32): log-decay and raw gate
    gemm_f32<3><<<dim3(KD_ / 64, M_ / 64), blk, 0, stream>>>(hidw, Ww_b, bw, db_, 64, 64, KD_, KD_);
    gemm_f32<2><<<dim3(KD_ / 64, M_ / 64), blk, 0, stream>>>(hidg, Wg_b, bg, gb_, 64, 64, KD_, KD_);

    // 5. r/k/v projections [bf16 MFMA] (overwrite consumed xm_w/xm_g regions)
    gemm_bf16t<0><<<dim3(KD_ / 64, M_ / 128), blk, 0, stream>>>(xmt_r, Wrt, rb_, H_, KD_);
    gemm_bf16t<0><<<dim3(KD_ / 64, M_ / 128), blk, 0, stream>>>(xmt_k, Wkt, kb_, H_, KD_);
    gemm_bf16t<0><<<dim3(KD_ / 64, M_ / 128), blk, 0, stream>>>(xmt_v, Wvt, vb_, H_, KD_);

    // 6. chunk-parallel scan (fp32)
    scan_chunkA<<<B_ * NH_ * NC_, blk, 0, stream>>>(rb_, kb_, vb_, db_, bonus,
                                                    rb_ /*rt in place*/, ob_, BS, Dc);
    scan_chunkB<<<(B_ * NH_ * 4096) / 256, blk, 0, stream>>>(BS, Dc);
    scan_chunkC<<<B_ * NH_ * NC_, blk, 0, stream>>>(rb_, BS, ob_);

    // 7. LN + swish gate -> tiled bf16 (xm region free again)
    lngate_kernel<<<(M_ * NH_) / 4, blk, 0, stream>>>(ob_, gb_, ln_w, ln_b, gt);

    // 8. out = gated @ Wo  [bf16 MFMA]
    gemm_bf16t<0><<<dim3(H_ / 64, M_ / 128), blk, 0, stream>>>(gt, Wot, out, KD_, H_);
}